// Round 4
// baseline (2391.572 us; speedup 1.0000x reference)
//
#include <hip/hip_runtime.h>
#include <math.h>

#define EF 128
#define NPTS 32768
#define KNN 8
#define MVOX 8192
#define GDIM 32
#define NVOXG (GDIM*GDIM*GDIM)

typedef __attribute__((ext_vector_type(8))) short bfrag;   // 8 x bf16
typedef __attribute__((ext_vector_type(4))) float f32x4;

__device__ __forceinline__ float lrelu(float x) { return x > 0.f ? x : 0.01f * x; }
__device__ __forceinline__ short f2b(float f) {            // fp32 -> bf16 (RNE)
    unsigned u = __float_as_uint(f);
    return (short)((u + 0x7fff + ((u >> 16) & 1)) >> 16);
}
#define MFMA(a,b,c) __builtin_amdgcn_mfma_f32_16x16x32_bf16((a),(b),(c),0,0,0)

// ---------------- weight packing: W[k][col] (strided) -> [step][ct][lane][8] bf16 ----------------
__global__ void k_pack_w(const float* __restrict__ src, short* __restrict__ dst,
                         int K_real, int n_steps, int k_str, int c_str) {
    int t = blockIdx.x * 256 + threadIdx.x;
    int total = n_steps * 4096;
    if (t >= total) return;
    int r = t & 7, l = (t >> 3) & 63, ct = (t >> 9) & 7, s = t >> 12;
    int k = s * 32 + (l >> 4) * 8 + r;
    int col = ct * 16 + (l & 15);
    float v = (k < K_real) ? src[(size_t)k * k_str + (size_t)col * c_str] : 0.f;
    dst[t] = f2b(v);
}
// conv3x3x3 weights [o][ci][27] -> [tap*4+cc][ct][lane][8]
__global__ void k_pack_wc1(const float* __restrict__ src, short* __restrict__ dst) {
    int t = blockIdx.x * 256 + threadIdx.x;
    if (t >= 108 * 4096) return;
    int r = t & 7, l = (t >> 3) & 63, ct = (t >> 9) & 7, s = t >> 12;
    int tap = s >> 2;
    int ci = (s & 3) * 32 + (l >> 4) * 8 + r;
    int col = ct * 16 + (l & 15);
    dst[t] = f2b(src[((size_t)col * 128 + ci) * 27 + tap]);
}

// ================= unified template: block = M-tile, 8 waves, wave = Mx16 cols =================

// ---------------- pc_conv_first: block M128, 8 waves ----------------
__global__ __launch_bounds__(512) void k_pcfirst(
    const float* __restrict__ xyz, const float* __restrict__ W1, const float* __restrict__ b1,
    const short* __restrict__ w2p, const float* __restrict__ b2,
    float* __restrict__ out32, short* __restrict__ out16) {
    __shared__ __align__(16) char tb[32768];
    int wid = threadIdx.x >> 6, lane = threadIdx.x & 63, lrow = lane & 15, lq = lane >> 4;
    int rowbase = blockIdx.x * 128;
    // layer 1 (3->128) on VALU: thread -> row tid>>2, cols (tid&3)*32..+31
    {
        int row = threadIdx.x >> 2;
        int grow = rowbase + row;
        int cb = (threadIdx.x & 3) * 32;
        float x0 = xyz[grow * 3], y0 = xyz[grow * 3 + 1], z0 = xyz[grow * 3 + 2];
        int rxor = (row & 7) << 4;
        #pragma unroll
        for (int j0 = 0; j0 < 32; j0 += 8) {
            bfrag v;
            #pragma unroll
            for (int j = 0; j < 8; ++j) {
                int col = cb + j0 + j;
                v[j] = f2b(lrelu(b1[col] + x0 * W1[col] + y0 * W1[128 + col] + z0 * W1[256 + col]));
            }
            *(bfrag*)(tb + row * 256 + (((cb + j0) * 2) ^ rxor)) = v;
        }
    }
    __syncthreads();
    float bb2 = b2[wid * 16 + lrow];
    f32x4 zv = {0.f, 0.f, 0.f, 0.f};
    f32x4 acc[8];
    #pragma unroll
    for (int rt = 0; rt < 8; ++rt) acc[rt] = zv;
    const bfrag* bp2 = (const bfrag*)w2p;
    #pragma unroll
    for (int s = 0; s < 4; ++s) {
        bfrag B = bp2[(s * 8 + wid) * 64 + lane];
        #pragma unroll
        for (int rt = 0; rt < 8; ++rt) {
            int row = rt * 16 + lrow;
            bfrag av = *(const bfrag*)(tb + row * 256 + (((s * 32 + lq * 8) * 2) ^ ((row & 7) << 4)));
            acc[rt] = MFMA(av, B, acc[rt]);
        }
    }
    #pragma unroll
    for (int rt = 0; rt < 8; ++rt) {
        float m = -INFINITY;
        #pragma unroll
        for (int r = 0; r < 4; ++r) m = fmaxf(m, acc[rt][r] + bb2);
        m = fmaxf(m, __shfl_xor(m, 16, 64));
        if ((lq & 1) == 0) {
            int p = (rowbase >> 3) + rt * 2 + (lq >> 1);
            float v = lrelu(m);
            out32[(size_t)p * 128 + wid * 16 + lrow] = v;
            out16[(size_t)p * 128 + wid * 16 + lrow] = f2b(v);
        }
    }
}

// ---------------- pc_conv: block M128, 8 waves; gather + 131->128 + 128->128 + maxpool ----------------
__global__ __launch_bounds__(512) void k_pcconv(
    const short* __restrict__ fin16, const int* __restrict__ idx, const float* __restrict__ xyz,
    const short* __restrict__ w1p, const float* __restrict__ b1,
    const short* __restrict__ w2p, const float* __restrict__ b2,
    float* __restrict__ out32, short* __restrict__ out16) {
    __shared__ __align__(16) char tb[32768];
    int wid = threadIdx.x >> 6, lane = threadIdx.x & 63, lrow = lane & 15, lq = lane >> 4;
    int rowbase = blockIdx.x * 128;
    int nb[8];
    #pragma unroll
    for (int rt = 0; rt < 8; ++rt) nb[rt] = idx[rowbase + rt * 16 + lrow];
    float bb1 = b1[wid * 16 + lrow], bb2 = b2[wid * 16 + lrow];
    f32x4 zv = {0.f, 0.f, 0.f, 0.f};
    f32x4 acc[8];
    #pragma unroll
    for (int rt = 0; rt < 8; ++rt) acc[rt] = zv;
    const bfrag* bp1 = (const bfrag*)w1p;
    #pragma unroll
    for (int s = 0; s < 4; ++s) {
        bfrag B = bp1[(s * 8 + wid) * 64 + lane];
        #pragma unroll
        for (int rt = 0; rt < 8; ++rt) {
            bfrag a = *((const bfrag*)(fin16 + (size_t)nb[rt] * 128) + s * 4 + lq);
            acc[rt] = MFMA(a, B, acc[rt]);
        }
    }
    {   // k-step 4: xyz concat (cols 128..130)
        bfrag B = bp1[(4 * 8 + wid) * 64 + lane];
        #pragma unroll
        for (int rt = 0; rt < 8; ++rt) {
            bfrag a4;
            #pragma unroll
            for (int r = 0; r < 8; ++r) a4[r] = 0;
            if (lq == 0) {
                int gr = rowbase + rt * 16 + lrow;
                a4[0] = f2b(xyz[gr * 3]); a4[1] = f2b(xyz[gr * 3 + 1]); a4[2] = f2b(xyz[gr * 3 + 2]);
            }
            acc[rt] = MFMA(a4, B, acc[rt]);
        }
    }
    #pragma unroll
    for (int rt = 0; rt < 8; ++rt)
        #pragma unroll
        for (int r = 0; r < 4; ++r) {
            int row = rt * 16 + lq * 4 + r, col = wid * 16 + lrow;
            *(short*)(tb + row * 256 + ((col * 2) ^ ((row & 7) << 4))) = f2b(lrelu(acc[rt][r] + bb1));
        }
    __syncthreads();
    f32x4 acc2[8];
    #pragma unroll
    for (int rt = 0; rt < 8; ++rt) acc2[rt] = zv;
    const bfrag* bp2 = (const bfrag*)w2p;
    #pragma unroll
    for (int s = 0; s < 4; ++s) {
        bfrag B = bp2[(s * 8 + wid) * 64 + lane];
        #pragma unroll
        for (int rt = 0; rt < 8; ++rt) {
            int row = rt * 16 + lrow;
            bfrag av = *(const bfrag*)(tb + row * 256 + (((s * 32 + lq * 8) * 2) ^ ((row & 7) << 4)));
            acc2[rt] = MFMA(av, B, acc2[rt]);
        }
    }
    #pragma unroll
    for (int rt = 0; rt < 8; ++rt) {
        float m = -INFINITY;
        #pragma unroll
        for (int r = 0; r < 4; ++r) m = fmaxf(m, acc2[rt][r] + bb2);
        m = fmaxf(m, __shfl_xor(m, 16, 64));
        if ((lq & 1) == 0) {
            int p = (rowbase >> 3) + rt * 2 + (lq >> 1);
            float v = lrelu(m);
            out32[(size_t)p * 128 + wid * 16 + lrow] = v;
            out16[(size_t)p * 128 + wid * 16 + lrow] = f2b(v);
        }
    }
}

// ---------------- pc_res: block M128, 8 waves ----------------
__global__ __launch_bounds__(512) void k_pcres(
    const float* __restrict__ fin32, const short* __restrict__ fin16,
    const short* __restrict__ w1p, const float* __restrict__ b1,
    const short* __restrict__ w2p, const float* __restrict__ b2,
    float* __restrict__ out32, short* __restrict__ out16) {
    __shared__ __align__(16) char tb[32768];
    int wid = threadIdx.x >> 6, lane = threadIdx.x & 63, lrow = lane & 15, lq = lane >> 4;
    int rowbase = blockIdx.x * 128;
    float bb1 = b1[wid * 16 + lrow], bb2 = b2[wid * 16 + lrow];
    f32x4 zv = {0.f, 0.f, 0.f, 0.f};
    f32x4 acc[8];
    #pragma unroll
    for (int rt = 0; rt < 8; ++rt) acc[rt] = zv;
    const bfrag* bp1 = (const bfrag*)w1p;
    #pragma unroll
    for (int s = 0; s < 4; ++s) {
        bfrag B = bp1[(s * 8 + wid) * 64 + lane];
        #pragma unroll
        for (int rt = 0; rt < 8; ++rt) {
            bfrag a = *((const bfrag*)(fin16 + (size_t)(rowbase + rt * 16 + lrow) * 128) + s * 4 + lq);
            acc[rt] = MFMA(a, B, acc[rt]);
        }
    }
    #pragma unroll
    for (int rt = 0; rt < 8; ++rt)
        #pragma unroll
        for (int r = 0; r < 4; ++r) {
            int row = rt * 16 + lq * 4 + r, col = wid * 16 + lrow;
            *(short*)(tb + row * 256 + ((col * 2) ^ ((row & 7) << 4))) = f2b(lrelu(acc[rt][r] + bb1));
        }
    __syncthreads();
    f32x4 acc2[8];
    #pragma unroll
    for (int rt = 0; rt < 8; ++rt) acc2[rt] = zv;
    const bfrag* bp2 = (const bfrag*)w2p;
    #pragma unroll
    for (int s = 0; s < 4; ++s) {
        bfrag B = bp2[(s * 8 + wid) * 64 + lane];
        #pragma unroll
        for (int rt = 0; rt < 8; ++rt) {
            int row = rt * 16 + lrow;
            bfrag av = *(const bfrag*)(tb + row * 256 + (((s * 32 + lq * 8) * 2) ^ ((row & 7) << 4)));
            acc2[rt] = MFMA(av, B, acc2[rt]);
        }
    }
    #pragma unroll
    for (int rt = 0; rt < 8; ++rt)
        #pragma unroll
        for (int r = 0; r < 4; ++r) {
            int row = rt * 16 + lq * 4 + r, col = wid * 16 + lrow;
            size_t o = (size_t)(rowbase + row) * 128 + col;
            float v = lrelu(acc2[rt][r] + bb2 + fin32[o]);
            out32[o] = v; out16[o] = f2b(v);
        }
}

// ---------------- conv3d 3x3x3: block = M64 voxels (2 b-lines), 8 waves; fused 1x1+res ----------------
__global__ __launch_bounds__(512) void k_conv3(
    const float* __restrict__ gin32, const short* __restrict__ gin16,
    const short* __restrict__ w1p, const float* __restrict__ b1,
    const short* __restrict__ w2p, const float* __restrict__ b2,
    float* __restrict__ gout32, short* __restrict__ gout16) {
    __shared__ __align__(16) char tb[16384];
    int wid = threadIdx.x >> 6, lane = threadIdx.x & 63, lrow = lane & 15, lq = lane >> 4;
    int va = blockIdx.x >> 4, vb0 = (blockIdx.x & 15) * 2;
    float bb1 = b1[wid * 16 + lrow], bb2 = b2[wid * 16 + lrow];
    f32x4 zv = {0.f, 0.f, 0.f, 0.f};
    f32x4 acc[4];
    #pragma unroll
    for (int rt = 0; rt < 4; ++rt) acc[rt] = zv;
    bfrag zf;
    #pragma unroll
    for (int r = 0; r < 8; ++r) zf[r] = 0;
    const bfrag* bp1 = (const bfrag*)w1p;
    #pragma unroll 1
    for (int tap = 0; tap < 27; ++tap) {
        bfrag Bt[4];                                   // prefetch this tap's B slice
        #pragma unroll
        for (int s = 0; s < 4; ++s) Bt[s] = bp1[((tap * 4 + s) * 8 + wid) * 64 + lane];
        int da = tap / 9 - 1, db = (tap / 3) % 3 - 1, dc = tap % 3 - 1;
        int aa = va + da;
        bool oka = (unsigned)aa < 32u;
        int aoff[4]; bool okr[4];
        #pragma unroll
        for (int rt = 0; rt < 4; ++rt) {
            int bl = vb0 + (rt >> 1) + db;
            int cc = (rt & 1) * 16 + lrow + dc;
            bool ok = oka && ((unsigned)bl < 32u) && ((unsigned)cc < 32u);
            aoff[rt] = ok ? ((aa * 32 + bl) * 32 + cc) * 128 : 0;
            okr[rt] = ok;
        }
        #pragma unroll
        for (int s = 0; s < 4; ++s) {
            bfrag a[4];
            #pragma unroll
            for (int rt = 0; rt < 4; ++rt) {
                bfrag t = *((const bfrag*)(gin16 + aoff[rt]) + s * 4 + lq);
                a[rt] = okr[rt] ? t : zf;
            }
            #pragma unroll
            for (int rt = 0; rt < 4; ++rt) acc[rt] = MFMA(a[rt], Bt[s], acc[rt]);
        }
    }
    #pragma unroll
    for (int rt = 0; rt < 4; ++rt)
        #pragma unroll
        for (int r = 0; r < 4; ++r) {
            int row = rt * 16 + lq * 4 + r, col = wid * 16 + lrow;
            *(short*)(tb + row * 256 + ((col * 2) ^ ((row & 7) << 4))) = f2b(lrelu(acc[rt][r] + bb1));
        }
    __syncthreads();
    f32x4 acc2[4];
    #pragma unroll
    for (int rt = 0; rt < 4; ++rt) acc2[rt] = zv;
    const bfrag* bp2 = (const bfrag*)w2p;
    #pragma unroll
    for (int s = 0; s < 4; ++s) {
        bfrag B = bp2[(s * 8 + wid) * 64 + lane];
        #pragma unroll
        for (int rt = 0; rt < 4; ++rt) {
            int row = rt * 16 + lrow;
            bfrag av = *(const bfrag*)(tb + row * 256 + (((s * 32 + lq * 8) * 2) ^ ((row & 7) << 4)));
            acc2[rt] = MFMA(av, B, acc2[rt]);
        }
    }
    #pragma unroll
    for (int rt = 0; rt < 4; ++rt)
        #pragma unroll
        for (int r = 0; r < 4; ++r) {
            int row = rt * 16 + lq * 4 + r;
            size_t o = (size_t)(((va * 32 + vb0 + (row >> 5)) * 32) + (row & 31)) * 128 + wid * 16 + lrow;
            float v = lrelu(acc2[rt][r] + bb2 + gin32[o]);
            gout32[o] = v; gout16[o] = f2b(v);
        }
}

// ---------------- head: gather + lin1 + lin2 + linb + sigmoid; block M64, 8 waves ----------------
__global__ __launch_bounds__(512) void k_head(
    const short* __restrict__ g16, const int* __restrict__ vx, const int* __restrict__ vmin,
    const short* __restrict__ w1p, const float* __restrict__ b1,
    const short* __restrict__ w2p, const float* __restrict__ b2,
    const float* __restrict__ W3, const float* __restrict__ b3,
    float* __restrict__ out) {
    __shared__ __align__(16) char tb[16384];
    __shared__ float t2[64][129];
    int wid = threadIdx.x >> 6, lane = threadIdx.x & 63, lrow = lane & 15, lq = lane >> 4;
    int rowbase = blockIdx.x * 64;
    int goff[4];
    #pragma unroll
    for (int rt = 0; rt < 4; ++rt) {
        int m = rowbase + rt * 16 + lrow;
        int v0 = vx[m * 3 + 0] - vmin[0];
        int v1 = vx[m * 3 + 1] - vmin[1];
        int v2 = vx[m * 3 + 2] - vmin[2];
        goff[rt] = ((v0 * 32 + v1) * 32 + v2) * 128;
    }
    float bb1 = b1[wid * 16 + lrow], bb2 = b2[wid * 16 + lrow];
    f32x4 zv = {0.f, 0.f, 0.f, 0.f};
    f32x4 acc[4];
    #pragma unroll
    for (int rt = 0; rt < 4; ++rt) acc[rt] = zv;
    const bfrag* bp1 = (const bfrag*)w1p;
    #pragma unroll
    for (int s = 0; s < 4; ++s) {
        bfrag B = bp1[(s * 8 + wid) * 64 + lane];
        #pragma unroll
        for (int rt = 0; rt < 4; ++rt) {
            bfrag a = *((const bfrag*)(g16 + goff[rt]) + s * 4 + lq);
            acc[rt] = MFMA(a, B, acc[rt]);
        }
    }
    #pragma unroll
    for (int rt = 0; rt < 4; ++rt)
        #pragma unroll
        for (int r = 0; r < 4; ++r) {
            int row = rt * 16 + lq * 4 + r, col = wid * 16 + lrow;
            *(short*)(tb + row * 256 + ((col * 2) ^ ((row & 7) << 4))) = f2b(lrelu(acc[rt][r] + bb1));
        }
    __syncthreads();
    f32x4 acc2[4];
    #pragma unroll
    for (int rt = 0; rt < 4; ++rt) acc2[rt] = zv;
    const bfrag* bp2 = (const bfrag*)w2p;
    #pragma unroll
    for (int s = 0; s < 4; ++s) {
        bfrag B = bp2[(s * 8 + wid) * 64 + lane];
        #pragma unroll
        for (int rt = 0; rt < 4; ++rt) {
            int row = rt * 16 + lrow;
            bfrag av = *(const bfrag*)(tb + row * 256 + (((s * 32 + lq * 8) * 2) ^ ((row & 7) << 4)));
            acc2[rt] = MFMA(av, B, acc2[rt]);
        }
    }
    #pragma unroll
    for (int rt = 0; rt < 4; ++rt)
        #pragma unroll
        for (int r = 0; r < 4; ++r) {
            int row = rt * 16 + lq * 4 + r, col = wid * 16 + lrow;
            t2[row][col] = lrelu(acc2[rt][r] + bb2);
        }
    __syncthreads();
    if (threadIdx.x < 192) {
        int row = threadIdx.x & 63, c = threadIdx.x >> 6;
        float s = b3[c];
        #pragma unroll 4
        for (int k = 0; k < 128; ++k) s += t2[row][k] * W3[k * 3 + c];
        out[(size_t)(rowbase + row) * 3 + c] = 1.f / (1.f + expf(-s));
    }
}

// ---------------- small kernels ----------------
__global__ void k_vmin(const int* __restrict__ vx, int M, int* __restrict__ vmin) {
    __shared__ int sm[3 * 256];
    int t = threadIdx.x;
    int m0 = 0x7fffffff, m1 = 0x7fffffff, m2 = 0x7fffffff;
    for (int i = t; i < M; i += 256) {
        m0 = min(m0, vx[i * 3 + 0]); m1 = min(m1, vx[i * 3 + 1]); m2 = min(m2, vx[i * 3 + 2]);
    }
    sm[t] = m0; sm[256 + t] = m1; sm[512 + t] = m2;
    __syncthreads();
    for (int s = 128; s > 0; s >>= 1) {
        if (t < s) {
            sm[t] = min(sm[t], sm[t + s]);
            sm[256 + t] = min(sm[256 + t], sm[256 + t + s]);
            sm[512 + t] = min(sm[512 + t], sm[512 + t + s]);
        }
        __syncthreads();
    }
    if (t == 0) { vmin[0] = sm[0]; vmin[1] = sm[256]; vmin[2] = sm[512]; }
}

__global__ void k_scatter(const float* __restrict__ vf, const int* __restrict__ vx,
                          const int* __restrict__ vmin, float* __restrict__ g32, short* __restrict__ g16) {
    int m = blockIdx.x, j = threadIdx.x;
    int v0 = vx[m * 3 + 0] - vmin[0];
    int v1 = vx[m * 3 + 1] - vmin[1];
    int v2 = vx[m * 3 + 2] - vmin[2];
    size_t o = (size_t)(((v0 * GDIM) + v1) * GDIM + v2) * EF + j;
    float v = vf[(size_t)m * EF + j];
    g32[o] = v; g16[o] = f2b(v);
}

extern "C" void kernel_launch(void* const* d_in, const int* in_sizes, int n_in,
                              void* d_out, int out_size, void* d_ws, size_t ws_size,
                              hipStream_t stream) {
    const int*   pc_idx  = (const int*)  d_in[0];
    const float* pc_xyz  = (const float*)d_in[1];
    const int*   vox_int = (const int*)  d_in[2];
    const int*   vox_idx = (const int*)  d_in[3];
    const float* vox_xyz = (const float*)d_in[4];
    const float* pcf_W1  = (const float*)d_in[5];
    const float* pcf_b1  = (const float*)d_in[6];
    const float* pcf_W2  = (const float*)d_in[7];
    const float* pcf_b2  = (const float*)d_in[8];
    const float* pcres_W1 = (const float*)d_in[9];
    const float* pcres_b1 = (const float*)d_in[10];
    const float* pcres_W2 = (const float*)d_in[11];
    const float* pcres_b2 = (const float*)d_in[12];
    const float* pcc_W1  = (const float*)d_in[13];
    const float* pcc_b1  = (const float*)d_in[14];
    const float* pcc_W2  = (const float*)d_in[15];
    const float* pcc_b2  = (const float*)d_in[16];
    const float* r3_Wc1  = (const float*)d_in[17];
    const float* r3_bc1  = (const float*)d_in[18];
    const float* r3_Wc2  = (const float*)d_in[19];
    const float* r3_bc2  = (const float*)d_in[20];
    const float* lin1_W  = (const float*)d_in[21];
    const float* lin1_b  = (const float*)d_in[22];
    const float* lin2_W  = (const float*)d_in[23];
    const float* lin2_b  = (const float*)d_in[24];
    const float* linb_W  = (const float*)d_in[25];
    const float* linb_b  = (const float*)d_in[26];

    const size_t NE = (size_t)NPTS * EF;   // 4M elements
    float* A32 = (float*)d_ws;
    float* B32 = A32 + NE;
    short* A16 = (short*)(B32 + NE);
    short* B16 = A16 + NE;
    float* Y32 = (float*)(B16 + NE);
    short* Y16 = (short*)(Y32 + NE);
    short* pcf_w2p = Y16 + NE;
    short* pcc_w1p = pcf_w2p + 4 * 4096;       // 6 layers x 5 steps
    short* pcc_w2p = pcc_w1p + 6 * 5 * 4096;   // 6 x 4
    short* pcr_w1p = pcc_w2p + 6 * 4 * 4096;   // 7 x 4
    short* pcr_w2p = pcr_w1p + 7 * 4 * 4096;
    short* wc2p    = pcr_w2p + 7 * 4 * 4096;   // 8 x 4
    short* lin1p   = wc2p    + 8 * 4 * 4096;
    short* lin2p   = lin1p   + 4 * 4096;
    short* wc1p    = lin2p   + 4 * 4096;       // 108 steps (one layer at a time)
    int*   vmin    = (int*)(wc1p + 108 * 4096);

    // ---- pack weights ----
    k_pack_w<<<64, 256, 0, stream>>>(pcf_W2, pcf_w2p, 128, 4, 128, 1);
    for (int i = 0; i < 6; ++i) {
        k_pack_w<<<80, 256, 0, stream>>>(pcc_W1 + (size_t)i * 131 * 128, pcc_w1p + (size_t)i * 5 * 4096, 131, 5, 128, 1);
        k_pack_w<<<64, 256, 0, stream>>>(pcc_W2 + (size_t)i * 128 * 128, pcc_w2p + (size_t)i * 4 * 4096, 128, 4, 128, 1);
    }
    for (int i = 0; i < 7; ++i) {
        k_pack_w<<<64, 256, 0, stream>>>(pcres_W1 + (size_t)i * 128 * 128, pcr_w1p + (size_t)i * 4 * 4096, 128, 4, 128, 1);
        k_pack_w<<<64, 256, 0, stream>>>(pcres_W2 + (size_t)i * 128 * 128, pcr_w2p + (size_t)i * 4 * 4096, 128, 4, 128, 1);
    }
    for (int i = 0; i < 8; ++i)
        k_pack_w<<<64, 256, 0, stream>>>(r3_Wc2 + (size_t)i * 128 * 128, wc2p + (size_t)i * 4 * 4096, 128, 4, 1, 128);
    k_pack_w<<<64, 256, 0, stream>>>(lin1_W, lin1p, 128, 4, 128, 1);
    k_pack_w<<<64, 256, 0, stream>>>(lin2_W, lin2p, 128, 4, 128, 1);

    // ---- point-cloud stack (A/B ping-pong; fp32 master + bf16 mirror) ----
    k_pcfirst<<<NPTS * KNN / 128, 512, 0, stream>>>(pc_xyz, pcf_W1, pcf_b1, pcf_w2p, pcf_b2, A32, A16);
    k_pcres<<<NPTS / 128, 512, 0, stream>>>(A32, A16, pcr_w1p, pcres_b1, pcr_w2p, pcres_b2, B32, B16);
    for (int i = 0; i < 5; ++i) {
        k_pcconv<<<NPTS * KNN / 128, 512, 0, stream>>>(B16, pc_idx, pc_xyz,
            pcc_w1p + (size_t)i * 5 * 4096, pcc_b1 + i * EF,
            pcc_w2p + (size_t)i * 4 * 4096, pcc_b2 + i * EF, A32, A16);
        k_pcres<<<NPTS / 128, 512, 0, stream>>>(A32, A16,
            pcr_w1p + (size_t)(i + 1) * 4 * 4096, pcres_b1 + (i + 1) * EF,
            pcr_w2p + (size_t)(i + 1) * 4 * 4096, pcres_b2 + (i + 1) * EF, B32, B16);
    }
    k_pcconv<<<MVOX * KNN / 128, 512, 0, stream>>>(B16, vox_idx, vox_xyz,
        pcc_w1p + (size_t)5 * 5 * 4096, pcc_b1 + 5 * EF,
        pcc_w2p + (size_t)5 * 4 * 4096, pcc_b2 + 5 * EF, A32, A16);
    k_pcres<<<MVOX / 128, 512, 0, stream>>>(A32, A16,
        pcr_w1p + (size_t)6 * 4 * 4096, pcres_b1 + 6 * EF,
        pcr_w2p + (size_t)6 * 4 * 4096, pcres_b2 + 6 * EF, B32, B16);
    // voxfeat now in B32 (rows 0..MVOX-1); A buffers dead -> reuse as grid X

    k_vmin<<<1, 256, 0, stream>>>(vox_int, MVOX, vmin);
    hipMemsetAsync(A32, 0, NE * sizeof(float), stream);
    hipMemsetAsync(A16, 0, NE * sizeof(short), stream);
    k_scatter<<<MVOX, 128, 0, stream>>>(B32, vox_int, vmin, A32, A16);

    // ---- 8 x resnet_block_rec3 (ping-pong A <-> Y) ----
    float* cur32 = A32; short* cur16 = A16;
    float* nxt32 = Y32; short* nxt16 = Y16;
    for (int i = 0; i < 8; ++i) {
        k_pack_wc1<<<1728, 256, 0, stream>>>(r3_Wc1 + (size_t)i * 128 * 128 * 27, wc1p);
        k_conv3<<<512, 512, 0, stream>>>(cur32, cur16, wc1p, r3_bc1 + i * EF,
                                         wc2p + (size_t)i * 4 * 4096, r3_bc2 + i * EF,
                                         nxt32, nxt16);
        float* t32 = cur32; cur32 = nxt32; nxt32 = t32;
        short* t16 = cur16; cur16 = nxt16; nxt16 = t16;
    }

    // ---- head ----
    k_head<<<MVOX / 64, 512, 0, stream>>>(cur16, vox_int, vmin,
                                          lin1p, lin1_b, lin2p, lin2_b, linb_W, linb_b,
                                          (float*)d_out);
}

// Round 5
// 1069.244 us; speedup vs baseline: 2.2367x; 2.2367x over previous
//
#include <hip/hip_runtime.h>
#include <math.h>

#define EF 128
#define NPTS 32768
#define KNN 8
#define MVOX 8192
#define GDIM 32
#define NVOXG (GDIM*GDIM*GDIM)

typedef __attribute__((ext_vector_type(8))) short bfrag;   // 8 x bf16
typedef __attribute__((ext_vector_type(4))) float f32x4;

__device__ __forceinline__ float lrelu(float x) { return x > 0.f ? x : 0.01f * x; }
__device__ __forceinline__ short f2b(float f) {            // fp32 -> bf16 (RNE)
    unsigned u = __float_as_uint(f);
    return (short)((u + 0x7fff + ((u >> 16) & 1)) >> 16);
}
#define MFMA(a,b,c) __builtin_amdgcn_mfma_f32_16x16x32_bf16((a),(b),(c),0,0,0)
// LDS tile addressing: row-major 256B rows, XOR swizzle on byte bits 4-6
__device__ __forceinline__ int swz(int row, int bytecol) {
    return row * 256 + (bytecol ^ ((row & 7) << 4));
}

// ---------------- weight packing: W[k][col] (strided) -> [step][ct][lane][8] bf16 ----------------
__global__ void k_pack_w(const float* __restrict__ src, short* __restrict__ dst,
                         int K_real, int n_steps, int k_str, int c_str) {
    int t = blockIdx.x * 256 + threadIdx.x;
    int total = n_steps * 4096;
    if (t >= total) return;
    int r = t & 7, l = (t >> 3) & 63, ct = (t >> 9) & 7, s = t >> 12;
    int k = s * 32 + (l >> 4) * 8 + r;
    int col = ct * 16 + (l & 15);
    float v = (k < K_real) ? src[(size_t)k * k_str + (size_t)col * c_str] : 0.f;
    dst[t] = f2b(v);
}
// conv3x3x3 weights [o][ci][27] -> [tap*4+cc][ct][lane][8]
__global__ void k_pack_wc1(const float* __restrict__ src, short* __restrict__ dst) {
    int t = blockIdx.x * 256 + threadIdx.x;
    if (t >= 108 * 4096) return;
    int r = t & 7, l = (t >> 3) & 63, ct = (t >> 9) & 7, s = t >> 12;
    int tap = s >> 2;
    int ci = (s & 3) * 32 + (l >> 4) * 8 + r;
    int col = ct * 16 + (l & 15);
    dst[t] = f2b(src[((size_t)col * 128 + ci) * 27 + tap]);
}

// ============ unified template: block = M128 x N128, 8 waves as 4M x 2N (wave M32 x N64) ============

// ---------------- pc_conv_first ----------------
__global__ __launch_bounds__(512) void k_pcfirst(
    const float* __restrict__ xyz, const float* __restrict__ W1, const float* __restrict__ b1,
    const short* __restrict__ w2p, const float* __restrict__ b2,
    float* __restrict__ out32, short* __restrict__ out16) {
    __shared__ __align__(16) char tb[32768];
    int wid = threadIdx.x >> 6, lane = threadIdx.x & 63, lrow = lane & 15, lq = lane >> 4;
    int wm = wid >> 1, wn = wid & 1;
    int rowbase = blockIdx.x * 128;
    // layer 1 (3->128) on VALU: thread -> row tid>>2, cols (tid&3)*32..+31
    {
        int row = threadIdx.x >> 2;
        int grow = rowbase + row;
        int cb = (threadIdx.x & 3) * 32;
        float x0 = xyz[grow * 3], y0 = xyz[grow * 3 + 1], z0 = xyz[grow * 3 + 2];
        #pragma unroll
        for (int j0 = 0; j0 < 32; j0 += 8) {
            bfrag v;
            #pragma unroll
            for (int j = 0; j < 8; ++j) {
                int col = cb + j0 + j;
                v[j] = f2b(lrelu(b1[col] + x0 * W1[col] + y0 * W1[128 + col] + z0 * W1[256 + col]));
            }
            *(bfrag*)(tb + swz(row, (cb + j0) * 2)) = v;
        }
    }
    __syncthreads();
    float bb2[4];
    #pragma unroll
    for (int ct = 0; ct < 4; ++ct) bb2[ct] = b2[wn * 64 + ct * 16 + lrow];
    f32x4 zv = {0.f, 0.f, 0.f, 0.f};
    f32x4 acc[2][4];
    #pragma unroll
    for (int rt = 0; rt < 2; ++rt)
        #pragma unroll
        for (int ct = 0; ct < 4; ++ct) acc[rt][ct] = zv;
    const bfrag* bp2 = (const bfrag*)w2p;
    #pragma unroll
    for (int s = 0; s < 4; ++s) {
        bfrag Bv[4];
        #pragma unroll
        for (int ct = 0; ct < 4; ++ct) Bv[ct] = bp2[(s * 8 + wn * 4 + ct) * 64 + lane];
        bfrag av[2];
        #pragma unroll
        for (int rt = 0; rt < 2; ++rt) {
            int row = wm * 32 + rt * 16 + lrow;
            av[rt] = *(const bfrag*)(tb + swz(row, s * 64 + lq * 16));
        }
        #pragma unroll
        for (int ct = 0; ct < 4; ++ct)
            #pragma unroll
            for (int rt = 0; rt < 2; ++rt) acc[rt][ct] = MFMA(av[rt], Bv[ct], acc[rt][ct]);
    }
    #pragma unroll
    for (int rt = 0; rt < 2; ++rt)
        #pragma unroll
        for (int ct = 0; ct < 4; ++ct) {
            float m = -INFINITY;
            #pragma unroll
            for (int r = 0; r < 4; ++r) m = fmaxf(m, acc[rt][ct][r] + bb2[ct]);
            m = fmaxf(m, __shfl_xor(m, 16, 64));
            if ((lq & 1) == 0) {
                int p = (rowbase >> 3) + wm * 4 + rt * 2 + (lq >> 1);
                float v = lrelu(m);
                out32[(size_t)p * 128 + wn * 64 + ct * 16 + lrow] = v;
                out16[(size_t)p * 128 + wn * 64 + ct * 16 + lrow] = f2b(v);
            }
        }
}

// ---------------- pc_conv: LDS-staged gather + 131->128 + 128->128 + maxpool ----------------
__global__ __launch_bounds__(512) void k_pcconv(
    const short* __restrict__ fin16, const int* __restrict__ idx, const float* __restrict__ xyz,
    const short* __restrict__ w1p, const float* __restrict__ b1,
    const short* __restrict__ w2p, const float* __restrict__ b2,
    float* __restrict__ out32, short* __restrict__ out16) {
    __shared__ __align__(16) char tb[32768];
    int wid = threadIdx.x >> 6, lane = threadIdx.x & 63, lrow = lane & 15, lq = lane >> 4;
    int wm = wid >> 1, wn = wid & 1;
    int rowbase = blockIdx.x * 128;
    // stage gathered rows once per block
    {
        int srow = threadIdx.x >> 2, sseg = threadIdx.x & 3;
        int nb = idx[rowbase + srow];
        const bfrag* src = (const bfrag*)(fin16 + (size_t)nb * 128);
        #pragma unroll
        for (int j = 0; j < 4; ++j) {
            int seg = sseg + j * 4;
            bfrag v = src[seg];
            *(bfrag*)(tb + swz(srow, seg * 16)) = v;
        }
    }
    __syncthreads();
    float bb1[4], bb2[4];
    #pragma unroll
    for (int ct = 0; ct < 4; ++ct) {
        bb1[ct] = b1[wn * 64 + ct * 16 + lrow];
        bb2[ct] = b2[wn * 64 + ct * 16 + lrow];
    }
    f32x4 zv = {0.f, 0.f, 0.f, 0.f};
    f32x4 acc[2][4];
    #pragma unroll
    for (int rt = 0; rt < 2; ++rt)
        #pragma unroll
        for (int ct = 0; ct < 4; ++ct) acc[rt][ct] = zv;
    const bfrag* bp1 = (const bfrag*)w1p;
    #pragma unroll
    for (int s = 0; s < 4; ++s) {
        bfrag Bv[4];
        #pragma unroll
        for (int ct = 0; ct < 4; ++ct) Bv[ct] = bp1[(s * 8 + wn * 4 + ct) * 64 + lane];
        bfrag av[2];
        #pragma unroll
        for (int rt = 0; rt < 2; ++rt) {
            int row = wm * 32 + rt * 16 + lrow;
            av[rt] = *(const bfrag*)(tb + swz(row, s * 64 + lq * 16));
        }
        #pragma unroll
        for (int ct = 0; ct < 4; ++ct)
            #pragma unroll
            for (int rt = 0; rt < 2; ++rt) acc[rt][ct] = MFMA(av[rt], Bv[ct], acc[rt][ct]);
    }
    {   // k-step 4: xyz concat (cols 128..130)
        bfrag Bv[4];
        #pragma unroll
        for (int ct = 0; ct < 4; ++ct) Bv[ct] = bp1[(32 + wn * 4 + ct) * 64 + lane];
        bfrag av[2];
        #pragma unroll
        for (int rt = 0; rt < 2; ++rt) {
            #pragma unroll
            for (int r = 0; r < 8; ++r) av[rt][r] = 0;
            if (lq == 0) {
                int gr = rowbase + wm * 32 + rt * 16 + lrow;
                av[rt][0] = f2b(xyz[gr * 3]); av[rt][1] = f2b(xyz[gr * 3 + 1]); av[rt][2] = f2b(xyz[gr * 3 + 2]);
            }
        }
        #pragma unroll
        for (int ct = 0; ct < 4; ++ct)
            #pragma unroll
            for (int rt = 0; rt < 2; ++rt) acc[rt][ct] = MFMA(av[rt], Bv[ct], acc[rt][ct]);
    }
    __syncthreads();   // all GEMM1 reads of tb done before overwrite
    #pragma unroll
    for (int rt = 0; rt < 2; ++rt)
        #pragma unroll
        for (int ct = 0; ct < 4; ++ct)
            #pragma unroll
            for (int r = 0; r < 4; ++r) {
                int row = wm * 32 + rt * 16 + lq * 4 + r, col = wn * 64 + ct * 16 + lrow;
                *(short*)(tb + swz(row, col * 2)) = f2b(lrelu(acc[rt][ct][r] + bb1[ct]));
            }
    __syncthreads();
    f32x4 acc2[2][4];
    #pragma unroll
    for (int rt = 0; rt < 2; ++rt)
        #pragma unroll
        for (int ct = 0; ct < 4; ++ct) acc2[rt][ct] = zv;
    const bfrag* bp2 = (const bfrag*)w2p;
    #pragma unroll
    for (int s = 0; s < 4; ++s) {
        bfrag Bv[4];
        #pragma unroll
        for (int ct = 0; ct < 4; ++ct) Bv[ct] = bp2[(s * 8 + wn * 4 + ct) * 64 + lane];
        bfrag av[2];
        #pragma unroll
        for (int rt = 0; rt < 2; ++rt) {
            int row = wm * 32 + rt * 16 + lrow;
            av[rt] = *(const bfrag*)(tb + swz(row, s * 64 + lq * 16));
        }
        #pragma unroll
        for (int ct = 0; ct < 4; ++ct)
            #pragma unroll
            for (int rt = 0; rt < 2; ++rt) acc2[rt][ct] = MFMA(av[rt], Bv[ct], acc2[rt][ct]);
    }
    #pragma unroll
    for (int rt = 0; rt < 2; ++rt)
        #pragma unroll
        for (int ct = 0; ct < 4; ++ct) {
            float m = -INFINITY;
            #pragma unroll
            for (int r = 0; r < 4; ++r) m = fmaxf(m, acc2[rt][ct][r] + bb2[ct]);
            m = fmaxf(m, __shfl_xor(m, 16, 64));
            if ((lq & 1) == 0) {
                int p = (rowbase >> 3) + wm * 4 + rt * 2 + (lq >> 1);
                float v = lrelu(m);
                out32[(size_t)p * 128 + wn * 64 + ct * 16 + lrow] = v;
                out16[(size_t)p * 128 + wn * 64 + ct * 16 + lrow] = f2b(v);
            }
        }
}

// ---------------- pc_res ----------------
__global__ __launch_bounds__(512) void k_pcres(
    const float* __restrict__ fin32, const short* __restrict__ fin16,
    const short* __restrict__ w1p, const float* __restrict__ b1,
    const short* __restrict__ w2p, const float* __restrict__ b2,
    float* __restrict__ out32, short* __restrict__ out16) {
    __shared__ __align__(16) char tb[32768];
    int wid = threadIdx.x >> 6, lane = threadIdx.x & 63, lrow = lane & 15, lq = lane >> 4;
    int wm = wid >> 1, wn = wid & 1;
    int rowbase = blockIdx.x * 128;
    float bb1[4], bb2[4];
    #pragma unroll
    for (int ct = 0; ct < 4; ++ct) {
        bb1[ct] = b1[wn * 64 + ct * 16 + lrow];
        bb2[ct] = b2[wn * 64 + ct * 16 + lrow];
    }
    f32x4 zv = {0.f, 0.f, 0.f, 0.f};
    f32x4 acc[2][4];
    #pragma unroll
    for (int rt = 0; rt < 2; ++rt)
        #pragma unroll
        for (int ct = 0; ct < 4; ++ct) acc[rt][ct] = zv;
    const bfrag* bp1 = (const bfrag*)w1p;
    #pragma unroll
    for (int s = 0; s < 4; ++s) {
        bfrag Bv[4];
        #pragma unroll
        for (int ct = 0; ct < 4; ++ct) Bv[ct] = bp1[(s * 8 + wn * 4 + ct) * 64 + lane];
        bfrag av[2];
        #pragma unroll
        for (int rt = 0; rt < 2; ++rt)
            av[rt] = *((const bfrag*)(fin16 + (size_t)(rowbase + wm * 32 + rt * 16 + lrow) * 128) + s * 4 + lq);
        #pragma unroll
        for (int ct = 0; ct < 4; ++ct)
            #pragma unroll
            for (int rt = 0; rt < 2; ++rt) acc[rt][ct] = MFMA(av[rt], Bv[ct], acc[rt][ct]);
    }
    #pragma unroll
    for (int rt = 0; rt < 2; ++rt)
        #pragma unroll
        for (int ct = 0; ct < 4; ++ct)
            #pragma unroll
            for (int r = 0; r < 4; ++r) {
                int row = wm * 32 + rt * 16 + lq * 4 + r, col = wn * 64 + ct * 16 + lrow;
                *(short*)(tb + swz(row, col * 2)) = f2b(lrelu(acc[rt][ct][r] + bb1[ct]));
            }
    __syncthreads();
    f32x4 acc2[2][4];
    #pragma unroll
    for (int rt = 0; rt < 2; ++rt)
        #pragma unroll
        for (int ct = 0; ct < 4; ++ct) acc2[rt][ct] = zv;
    const bfrag* bp2 = (const bfrag*)w2p;
    #pragma unroll
    for (int s = 0; s < 4; ++s) {
        bfrag Bv[4];
        #pragma unroll
        for (int ct = 0; ct < 4; ++ct) Bv[ct] = bp2[(s * 8 + wn * 4 + ct) * 64 + lane];
        bfrag av[2];
        #pragma unroll
        for (int rt = 0; rt < 2; ++rt) {
            int row = wm * 32 + rt * 16 + lrow;
            av[rt] = *(const bfrag*)(tb + swz(row, s * 64 + lq * 16));
        }
        #pragma unroll
        for (int ct = 0; ct < 4; ++ct)
            #pragma unroll
            for (int rt = 0; rt < 2; ++rt) acc2[rt][ct] = MFMA(av[rt], Bv[ct], acc2[rt][ct]);
    }
    #pragma unroll
    for (int rt = 0; rt < 2; ++rt)
        #pragma unroll
        for (int ct = 0; ct < 4; ++ct)
            #pragma unroll
            for (int r = 0; r < 4; ++r) {
                int row = wm * 32 + rt * 16 + lq * 4 + r, col = wn * 64 + ct * 16 + lrow;
                size_t o = (size_t)(rowbase + row) * 128 + col;
                float v = lrelu(acc2[rt][ct][r] + bb2[ct] + fin32[o]);
                out32[o] = v; out16[o] = f2b(v);
            }
}

// ---------------- conv3d 3x3x3: per-tap double-buffered LDS A-staging; fused 1x1 + residual ----------------
__global__ __launch_bounds__(512) void k_conv3(
    const float* __restrict__ gin32, const short* __restrict__ gin16,
    const short* __restrict__ w1p, const float* __restrict__ b1,
    const short* __restrict__ w2p, const float* __restrict__ b2,
    float* __restrict__ gout32, short* __restrict__ gout16) {
    __shared__ __align__(16) char Ab[2][32768];
    int wid = threadIdx.x >> 6, lane = threadIdx.x & 63, lrow = lane & 15, lq = lane >> 4;
    int wm = wid >> 1, wn = wid & 1;
    int va = blockIdx.x >> 3, vb0 = (blockIdx.x & 7) * 4;
    int srow = threadIdx.x >> 2, sseg = threadIdx.x & 3;
    int sb = srow >> 5, sc = srow & 31;                 // staging row -> (b-line, c)
    bfrag zf;
    #pragma unroll
    for (int r = 0; r < 8; ++r) zf[r] = 0;
    float bb1[4], bb2[4];
    #pragma unroll
    for (int ct = 0; ct < 4; ++ct) {
        bb1[ct] = b1[wn * 64 + ct * 16 + lrow];
        bb2[ct] = b2[wn * 64 + ct * 16 + lrow];
    }
    f32x4 zv = {0.f, 0.f, 0.f, 0.f};
    f32x4 acc[2][4];
    #pragma unroll
    for (int rt = 0; rt < 2; ++rt)
        #pragma unroll
        for (int ct = 0; ct < 4; ++ct) acc[rt][ct] = zv;
    const bfrag* bp1 = (const bfrag*)w1p;

    // prologue: stage tap 0 (da=db=dc=-1)
    {
        int aa = va - 1, bb = vb0 + sb - 1, cc = sc - 1;
        bool ok = ((unsigned)aa < 32u) && ((unsigned)bb < 32u) && ((unsigned)cc < 32u);
        int soff = ok ? ((aa * 32 + bb) * 32 + cc) * 128 : 0;
        const bfrag* src = (const bfrag*)(gin16 + soff);
        #pragma unroll
        for (int j = 0; j < 4; ++j) {
            int seg = sseg + j * 4;
            bfrag v = src[seg];
            *(bfrag*)(Ab[0] + swz(srow, seg * 16)) = ok ? v : zf;
        }
    }
    __syncthreads();

    #pragma unroll 1
    for (int tap = 0; tap < 27; ++tap) {
        // issue next-tap stage loads early (complete under this tap's MFMA window)
        bfrag st[4];
        bool okn = false;
        if (tap < 26) {
            int tn = tap + 1;
            int da = tn / 9 - 1, db = (tn / 3) % 3 - 1, dc = tn % 3 - 1;
            int aa = va + da, bb = vb0 + sb + db, cc = sc + dc;
            okn = ((unsigned)aa < 32u) && ((unsigned)bb < 32u) && ((unsigned)cc < 32u);
            int soff = okn ? ((aa * 32 + bb) * 32 + cc) * 128 : 0;
            const bfrag* src = (const bfrag*)(gin16 + soff);
            #pragma unroll
            for (int j = 0; j < 4; ++j) st[j] = src[sseg + j * 4];
        }
        // compute current tap from Ab[tap&1]
        const char* tbc = Ab[tap & 1];
        #pragma unroll
        for (int s = 0; s < 4; ++s) {
            bfrag Bv[4];
            #pragma unroll
            for (int ct = 0; ct < 4; ++ct) Bv[ct] = bp1[((tap * 4 + s) * 8 + wn * 4 + ct) * 64 + lane];
            bfrag av[2];
            #pragma unroll
            for (int rt = 0; rt < 2; ++rt) {
                int row = wm * 32 + rt * 16 + lrow;
                av[rt] = *(const bfrag*)(tbc + swz(row, s * 64 + lq * 16));
            }
            #pragma unroll
            for (int ct = 0; ct < 4; ++ct)
                #pragma unroll
                for (int rt = 0; rt < 2; ++rt) acc[rt][ct] = MFMA(av[rt], Bv[ct], acc[rt][ct]);
        }
        // write staged rows into the other buffer
        if (tap < 26) {
            char* nb = Ab[(tap + 1) & 1];
            #pragma unroll
            for (int j = 0; j < 4; ++j)
                *(bfrag*)(nb + swz(srow, (sseg + j * 4) * 16)) = okn ? st[j] : zf;
        }
        __syncthreads();
    }

    // epilogue: bias+lrelu -> t tile (reuse Ab[0]); then fused 1x1 + residual
    #pragma unroll
    for (int rt = 0; rt < 2; ++rt)
        #pragma unroll
        for (int ct = 0; ct < 4; ++ct)
            #pragma unroll
            for (int r = 0; r < 4; ++r) {
                int row = wm * 32 + rt * 16 + lq * 4 + r, col = wn * 64 + ct * 16 + lrow;
                *(short*)(Ab[0] + swz(row, col * 2)) = f2b(lrelu(acc[rt][ct][r] + bb1[ct]));
            }
    __syncthreads();
    f32x4 acc2[2][4];
    #pragma unroll
    for (int rt = 0; rt < 2; ++rt)
        #pragma unroll
        for (int ct = 0; ct < 4; ++ct) acc2[rt][ct] = zv;
    const bfrag* bp2 = (const bfrag*)w2p;
    #pragma unroll
    for (int s = 0; s < 4; ++s) {
        bfrag Bv[4];
        #pragma unroll
        for (int ct = 0; ct < 4; ++ct) Bv[ct] = bp2[(s * 8 + wn * 4 + ct) * 64 + lane];
        bfrag av[2];
        #pragma unroll
        for (int rt = 0; rt < 2; ++rt) {
            int row = wm * 32 + rt * 16 + lrow;
            av[rt] = *(const bfrag*)(Ab[0] + swz(row, s * 64 + lq * 16));
        }
        #pragma unroll
        for (int ct = 0; ct < 4; ++ct)
            #pragma unroll
            for (int rt = 0; rt < 2; ++rt) acc2[rt][ct] = MFMA(av[rt], Bv[ct], acc2[rt][ct]);
    }
    #pragma unroll
    for (int rt = 0; rt < 2; ++rt)
        #pragma unroll
        for (int ct = 0; ct < 4; ++ct)
            #pragma unroll
            for (int r = 0; r < 4; ++r) {
                int row = wm * 32 + rt * 16 + lq * 4 + r;
                int voxel = (va * 32 + vb0 + (row >> 5)) * 32 + (row & 31);
                size_t o = (size_t)voxel * 128 + wn * 64 + ct * 16 + lrow;
                float v = lrelu(acc2[rt][ct][r] + bb2[ct] + gin32[o]);
                gout32[o] = v; gout16[o] = f2b(v);
            }
}

// ---------------- head: gather + lin1 + lin2 + linb + sigmoid; block M64, 8 waves ----------------
__global__ __launch_bounds__(512) void k_head(
    const short* __restrict__ g16, const int* __restrict__ vx, const int* __restrict__ vmin,
    const short* __restrict__ w1p, const float* __restrict__ b1,
    const short* __restrict__ w2p, const float* __restrict__ b2,
    const float* __restrict__ W3, const float* __restrict__ b3,
    float* __restrict__ out) {
    __shared__ __align__(16) char tb[16384];
    __shared__ float t2[64][129];
    int wid = threadIdx.x >> 6, lane = threadIdx.x & 63, lrow = lane & 15, lq = lane >> 4;
    int rowbase = blockIdx.x * 64;
    int goff[4];
    #pragma unroll
    for (int rt = 0; rt < 4; ++rt) {
        int m = rowbase + rt * 16 + lrow;
        int v0 = vx[m * 3 + 0] - vmin[0];
        int v1 = vx[m * 3 + 1] - vmin[1];
        int v2 = vx[m * 3 + 2] - vmin[2];
        goff[rt] = ((v0 * 32 + v1) * 32 + v2) * 128;
    }
    float bb1 = b1[wid * 16 + lrow], bb2 = b2[wid * 16 + lrow];
    f32x4 zv = {0.f, 0.f, 0.f, 0.f};
    f32x4 acc[4];
    #pragma unroll
    for (int rt = 0; rt < 4; ++rt) acc[rt] = zv;
    const bfrag* bp1 = (const bfrag*)w1p;
    #pragma unroll
    for (int s = 0; s < 4; ++s) {
        bfrag B = bp1[(s * 8 + wid) * 64 + lane];
        #pragma unroll
        for (int rt = 0; rt < 4; ++rt) {
            bfrag a = *((const bfrag*)(g16 + goff[rt]) + s * 4 + lq);
            acc[rt] = MFMA(a, B, acc[rt]);
        }
    }
    #pragma unroll
    for (int rt = 0; rt < 4; ++rt)
        #pragma unroll
        for (int r = 0; r < 4; ++r) {
            int row = rt * 16 + lq * 4 + r, col = wid * 16 + lrow;
            *(short*)(tb + swz(row, col * 2)) = f2b(lrelu(acc[rt][r] + bb1));
        }
    __syncthreads();
    f32x4 acc2[4];
    #pragma unroll
    for (int rt = 0; rt < 4; ++rt) acc2[rt] = zv;
    const bfrag* bp2 = (const bfrag*)w2p;
    #pragma unroll
    for (int s = 0; s < 4; ++s) {
        bfrag B = bp2[(s * 8 + wid) * 64 + lane];
        #pragma unroll
        for (int rt = 0; rt < 4; ++rt) {
            int row = rt * 16 + lrow;
            bfrag av = *(const bfrag*)(tb + swz(row, s * 64 + lq * 16));
            acc2[rt] = MFMA(av, B, acc2[rt]);
        }
    }
    #pragma unroll
    for (int rt = 0; rt < 4; ++rt)
        #pragma unroll
        for (int r = 0; r < 4; ++r) {
            int row = rt * 16 + lq * 4 + r, col = wid * 16 + lrow;
            t2[row][col] = lrelu(acc2[rt][r] + bb2);
        }
    __syncthreads();
    if (threadIdx.x < 192) {
        int row = threadIdx.x & 63, c = threadIdx.x >> 6;
        float s = b3[c];
        #pragma unroll 4
        for (int k = 0; k < 128; ++k) s += t2[row][k] * W3[k * 3 + c];
        out[(size_t)(rowbase + row) * 3 + c] = 1.f / (1.f + expf(-s));
    }
}

// ---------------- small kernels ----------------
__global__ void k_vmin(const int* __restrict__ vx, int M, int* __restrict__ vmin) {
    __shared__ int sm[3 * 256];
    int t = threadIdx.x;
    int m0 = 0x7fffffff, m1 = 0x7fffffff, m2 = 0x7fffffff;
    for (int i = t; i < M; i += 256) {
        m0 = min(m0, vx[i * 3 + 0]); m1 = min(m1, vx[i * 3 + 1]); m2 = min(m2, vx[i * 3 + 2]);
    }
    sm[t] = m0; sm[256 + t] = m1; sm[512 + t] = m2;
    __syncthreads();
    for (int s = 128; s > 0; s >>= 1) {
        if (t < s) {
            sm[t] = min(sm[t], sm[t + s]);
            sm[256 + t] = min(sm[256 + t], sm[256 + t + s]);
            sm[512 + t] = min(sm[512 + t], sm[512 + t + s]);
        }
        __syncthreads();
    }
    if (t == 0) { vmin[0] = sm[0]; vmin[1] = sm[256]; vmin[2] = sm[512]; }
}

__global__ void k_scatter(const float* __restrict__ vf, const int* __restrict__ vx,
                          const int* __restrict__ vmin, float* __restrict__ g32, short* __restrict__ g16) {
    int m = blockIdx.x, j = threadIdx.x;
    int v0 = vx[m * 3 + 0] - vmin[0];
    int v1 = vx[m * 3 + 1] - vmin[1];
    int v2 = vx[m * 3 + 2] - vmin[2];
    size_t o = (size_t)(((v0 * GDIM) + v1) * GDIM + v2) * EF + j;
    float v = vf[(size_t)m * EF + j];
    g32[o] = v; g16[o] = f2b(v);
}

extern "C" void kernel_launch(void* const* d_in, const int* in_sizes, int n_in,
                              void* d_out, int out_size, void* d_ws, size_t ws_size,
                              hipStream_t stream) {
    const int*   pc_idx  = (const int*)  d_in[0];
    const float* pc_xyz  = (const float*)d_in[1];
    const int*   vox_int = (const int*)  d_in[2];
    const int*   vox_idx = (const int*)  d_in[3];
    const float* vox_xyz = (const float*)d_in[4];
    const float* pcf_W1  = (const float*)d_in[5];
    const float* pcf_b1  = (const float*)d_in[6];
    const float* pcf_W2  = (const float*)d_in[7];
    const float* pcf_b2  = (const float*)d_in[8];
    const float* pcres_W1 = (const float*)d_in[9];
    const float* pcres_b1 = (const float*)d_in[10];
    const float* pcres_W2 = (const float*)d_in[11];
    const float* pcres_b2 = (const float*)d_in[12];
    const float* pcc_W1  = (const float*)d_in[13];
    const float* pcc_b1  = (const float*)d_in[14];
    const float* pcc_W2  = (const float*)d_in[15];
    const float* pcc_b2  = (const float*)d_in[16];
    const float* r3_Wc1  = (const float*)d_in[17];
    const float* r3_bc1  = (const float*)d_in[18];
    const float* r3_Wc2  = (const float*)d_in[19];
    const float* r3_bc2  = (const float*)d_in[20];
    const float* lin1_W  = (const float*)d_in[21];
    const float* lin1_b  = (const float*)d_in[22];
    const float* lin2_W  = (const float*)d_in[23];
    const float* lin2_b  = (const float*)d_in[24];
    const float* linb_W  = (const float*)d_in[25];
    const float* linb_b  = (const float*)d_in[26];

    const size_t NE = (size_t)NPTS * EF;   // 4M elements
    float* A32 = (float*)d_ws;
    float* B32 = A32 + NE;
    short* A16 = (short*)(B32 + NE);
    short* B16 = A16 + NE;
    float* Y32 = (float*)(B16 + NE);
    short* Y16 = (short*)(Y32 + NE);
    short* pcf_w2p = Y16 + NE;
    short* pcc_w1p = pcf_w2p + 4 * 4096;       // 6 layers x 5 steps
    short* pcc_w2p = pcc_w1p + 6 * 5 * 4096;   // 6 x 4
    short* pcr_w1p = pcc_w2p + 6 * 4 * 4096;   // 7 x 4
    short* pcr_w2p = pcr_w1p + 7 * 4 * 4096;
    short* wc2p    = pcr_w2p + 7 * 4 * 4096;   // 8 x 4
    short* lin1p   = wc2p    + 8 * 4 * 4096;
    short* lin2p   = lin1p   + 4 * 4096;
    short* wc1p    = lin2p   + 4 * 4096;       // 108 steps (one layer at a time)
    int*   vmin    = (int*)(wc1p + 108 * 4096);

    // ---- pack weights ----
    k_pack_w<<<64, 256, 0, stream>>>(pcf_W2, pcf_w2p, 128, 4, 128, 1);
    for (int i = 0; i < 6; ++i) {
        k_pack_w<<<80, 256, 0, stream>>>(pcc_W1 + (size_t)i * 131 * 128, pcc_w1p + (size_t)i * 5 * 4096, 131, 5, 128, 1);
        k_pack_w<<<64, 256, 0, stream>>>(pcc_W2 + (size_t)i * 128 * 128, pcc_w2p + (size_t)i * 4 * 4096, 128, 4, 128, 1);
    }
    for (int i = 0; i < 7; ++i) {
        k_pack_w<<<64, 256, 0, stream>>>(pcres_W1 + (size_t)i * 128 * 128, pcr_w1p + (size_t)i * 4 * 4096, 128, 4, 128, 1);
        k_pack_w<<<64, 256, 0, stream>>>(pcres_W2 + (size_t)i * 128 * 128, pcr_w2p + (size_t)i * 4 * 4096, 128, 4, 128, 1);
    }
    for (int i = 0; i < 8; ++i)
        k_pack_w<<<64, 256, 0, stream>>>(r3_Wc2 + (size_t)i * 128 * 128, wc2p + (size_t)i * 4 * 4096, 128, 4, 1, 128);
    k_pack_w<<<64, 256, 0, stream>>>(lin1_W, lin1p, 128, 4, 128, 1);
    k_pack_w<<<64, 256, 0, stream>>>(lin2_W, lin2p, 128, 4, 128, 1);

    // ---- point-cloud stack (A/B ping-pong; fp32 master + bf16 mirror) ----
    k_pcfirst<<<NPTS * KNN / 128, 512, 0, stream>>>(pc_xyz, pcf_W1, pcf_b1, pcf_w2p, pcf_b2, A32, A16);
    k_pcres<<<NPTS / 128, 512, 0, stream>>>(A32, A16, pcr_w1p, pcres_b1, pcr_w2p, pcres_b2, B32, B16);
    for (int i = 0; i < 5; ++i) {
        k_pcconv<<<NPTS * KNN / 128, 512, 0, stream>>>(B16, pc_idx, pc_xyz,
            pcc_w1p + (size_t)i * 5 * 4096, pcc_b1 + i * EF,
            pcc_w2p + (size_t)i * 4 * 4096, pcc_b2 + i * EF, A32, A16);
        k_pcres<<<NPTS / 128, 512, 0, stream>>>(A32, A16,
            pcr_w1p + (size_t)(i + 1) * 4 * 4096, pcres_b1 + (i + 1) * EF,
            pcr_w2p + (size_t)(i + 1) * 4 * 4096, pcres_b2 + (i + 1) * EF, B32, B16);
    }
    k_pcconv<<<MVOX * KNN / 128, 512, 0, stream>>>(B16, vox_idx, vox_xyz,
        pcc_w1p + (size_t)5 * 5 * 4096, pcc_b1 + 5 * EF,
        pcc_w2p + (size_t)5 * 4 * 4096, pcc_b2 + 5 * EF, A32, A16);
    k_pcres<<<MVOX / 128, 512, 0, stream>>>(A32, A16,
        pcr_w1p + (size_t)6 * 4 * 4096, pcres_b1 + 6 * EF,
        pcr_w2p + (size_t)6 * 4 * 4096, pcres_b2 + 6 * EF, B32, B16);
    // voxfeat now in B32 (rows 0..MVOX-1); A buffers dead -> reuse as grid X

    k_vmin<<<1, 256, 0, stream>>>(vox_int, MVOX, vmin);
    hipMemsetAsync(A32, 0, NE * sizeof(float), stream);
    hipMemsetAsync(A16, 0, NE * sizeof(short), stream);
    k_scatter<<<MVOX, 128, 0, stream>>>(B32, vox_int, vmin, A32, A16);

    // ---- 8 x resnet_block_rec3 (ping-pong A <-> Y) ----
    float* cur32 = A32; short* cur16 = A16;
    float* nxt32 = Y32; short* nxt16 = Y16;
    for (int i = 0; i < 8; ++i) {
        k_pack_wc1<<<1728, 256, 0, stream>>>(r3_Wc1 + (size_t)i * 128 * 128 * 27, wc1p);
        k_conv3<<<256, 512, 0, stream>>>(cur32, cur16, wc1p, r3_bc1 + i * EF,
                                         wc2p + (size_t)i * 4 * 4096, r3_bc2 + i * EF,
                                         nxt32, nxt16);
        float* t32 = cur32; cur32 = nxt32; nxt32 = t32;
        short* t16 = cur16; cur16 = nxt16; nxt16 = t16;
    }

    // ---- head ----
    k_head<<<MVOX / 64, 512, 0, stream>>>(cur16, vox_int, vmin,
                                          lin1p, lin1_b, lin2p, lin2_b, linb_W, linb_b,
                                          (float*)d_out);
}

// Round 6
// 853.394 us; speedup vs baseline: 2.8024x; 1.2529x over previous
//
#include <hip/hip_runtime.h>
#include <math.h>

#define EF 128
#define NPTS 32768
#define KNN 8
#define MVOX 8192
#define GDIM 32
#define NVOXG (GDIM*GDIM*GDIM)

typedef __attribute__((ext_vector_type(8))) short bfrag;   // 8 x bf16
typedef __attribute__((ext_vector_type(4))) float f32x4;

__device__ __forceinline__ float lrelu(float x) { return x > 0.f ? x : 0.01f * x; }
__device__ __forceinline__ short f2b(float f) {            // fp32 -> bf16 (RNE)
    unsigned u = __float_as_uint(f);
    return (short)((u + 0x7fff + ((u >> 16) & 1)) >> 16);
}
#define MFMA(a,b,c) __builtin_amdgcn_mfma_f32_16x16x32_bf16((a),(b),(c),0,0,0)
// LDS tile addressing: row-major 256B rows, XOR swizzle on byte bits 4-6
__device__ __forceinline__ int swz(int row, int bytecol) {
    return row * 256 + (bytecol ^ ((row & 7) << 4));
}

// ---------------- weight packing: W[k][col] (strided) -> [step][ct][lane][8] bf16 ----------------
__global__ void k_pack_w(const float* __restrict__ src, short* __restrict__ dst,
                         int K_real, int n_steps, int k_str, int c_str) {
    int t = blockIdx.x * 256 + threadIdx.x;
    int total = n_steps * 4096;
    if (t >= total) return;
    int r = t & 7, l = (t >> 3) & 63, ct = (t >> 9) & 7, s = t >> 12;
    int k = s * 32 + (l >> 4) * 8 + r;
    int col = ct * 16 + (l & 15);
    float v = (k < K_real) ? src[(size_t)k * k_str + (size_t)col * c_str] : 0.f;
    dst[t] = f2b(v);
}
// conv3x3x3 weights [o][ci][27] -> [tap*4+cc][ct][lane][8]
__global__ void k_pack_wc1(const float* __restrict__ src, short* __restrict__ dst) {
    int t = blockIdx.x * 256 + threadIdx.x;
    if (t >= 108 * 4096) return;
    int r = t & 7, l = (t >> 3) & 63, ct = (t >> 9) & 7, s = t >> 12;
    int tap = s >> 2;
    int ci = (s & 3) * 32 + (l >> 4) * 8 + r;
    int col = ct * 16 + (l & 15);
    dst[t] = f2b(src[((size_t)col * 128 + ci) * 27 + tap]);
}

// ============ unified template: block rows, 8 waves as 2M x 4N (wave M?x N32, ct=2) ============

// ---------------- pc_conv_first: block M128 ----------------
__global__ __launch_bounds__(512) void k_pcfirst(
    const float* __restrict__ xyz, const float* __restrict__ W1, const float* __restrict__ b1,
    const short* __restrict__ w2p, const float* __restrict__ b2,
    float* __restrict__ out32, short* __restrict__ out16) {
    __shared__ __align__(16) char tb[32768];
    int wid = threadIdx.x >> 6, lane = threadIdx.x & 63, lrow = lane & 15, lq = lane >> 4;
    int wm = wid >> 2, wn = wid & 3;
    int rowbase = blockIdx.x * 128;
    // layer 1 (3->128) on VALU, float4-vectorized weight loads
    {
        int row = threadIdx.x >> 2;
        int grow = rowbase + row;
        int cb = (threadIdx.x & 3) * 32;
        float x0 = xyz[grow * 3], y0 = xyz[grow * 3 + 1], z0 = xyz[grow * 3 + 2];
        f32x4 b1r[8], w0r[8], w1r[8], w2r[8];
        #pragma unroll
        for (int q = 0; q < 8; ++q) {
            b1r[q] = ((const f32x4*)(b1 + cb))[q];
            w0r[q] = ((const f32x4*)(W1 + cb))[q];
            w1r[q] = ((const f32x4*)(W1 + 128 + cb))[q];
            w2r[q] = ((const f32x4*)(W1 + 256 + cb))[q];
        }
        #pragma unroll
        for (int j0 = 0; j0 < 4; ++j0) {       // 8 cols per iter
            bfrag v;
            #pragma unroll
            for (int j = 0; j < 8; ++j) {
                int q = j0 * 2 + (j >> 2), e = j & 3;
                v[j] = f2b(lrelu(b1r[q][e] + x0 * w0r[q][e] + y0 * w1r[q][e] + z0 * w2r[q][e]));
            }
            *(bfrag*)(tb + swz(row, (cb + j0 * 8) * 2)) = v;
        }
    }
    __syncthreads();
    float bb2[2];
    #pragma unroll
    for (int ct = 0; ct < 2; ++ct) bb2[ct] = b2[wn * 32 + ct * 16 + lrow];
    f32x4 zv = {0.f, 0.f, 0.f, 0.f};
    f32x4 acc[4][2];
    #pragma unroll
    for (int rt = 0; rt < 4; ++rt) { acc[rt][0] = zv; acc[rt][1] = zv; }
    const bfrag* bp2 = (const bfrag*)w2p;
    #pragma unroll
    for (int s = 0; s < 4; ++s) {
        bfrag Bv[2];
        #pragma unroll
        for (int ct = 0; ct < 2; ++ct) Bv[ct] = bp2[(s * 8 + wn * 2 + ct) * 64 + lane];
        bfrag av[4];
        #pragma unroll
        for (int rt = 0; rt < 4; ++rt) {
            int row = wm * 64 + rt * 16 + lrow;
            av[rt] = *(const bfrag*)(tb + swz(row, s * 64 + lq * 16));
        }
        #pragma unroll
        for (int ct = 0; ct < 2; ++ct)
            #pragma unroll
            for (int rt = 0; rt < 4; ++rt) acc[rt][ct] = MFMA(av[rt], Bv[ct], acc[rt][ct]);
    }
    #pragma unroll
    for (int rt = 0; rt < 4; ++rt)
        #pragma unroll
        for (int ct = 0; ct < 2; ++ct) {
            float m = -INFINITY;
            #pragma unroll
            for (int r = 0; r < 4; ++r) m = fmaxf(m, acc[rt][ct][r] + bb2[ct]);
            m = fmaxf(m, __shfl_xor(m, 16, 64));
            if ((lq & 1) == 0) {
                int p = (rowbase >> 3) + wm * 8 + rt * 2 + (lq >> 1);
                float v = lrelu(m);
                out32[(size_t)p * 128 + wn * 32 + ct * 16 + lrow] = v;
                out16[(size_t)p * 128 + wn * 32 + ct * 16 + lrow] = f2b(v);
            }
        }
}

// ---------------- pc_conv: block M128; LDS-staged gather + 131->128 + 128->128 + maxpool ----------------
__global__ __launch_bounds__(512) void k_pcconv(
    const short* __restrict__ fin16, const int* __restrict__ idx, const float* __restrict__ xyz,
    const short* __restrict__ w1p, const float* __restrict__ b1,
    const short* __restrict__ w2p, const float* __restrict__ b2,
    float* __restrict__ out32, short* __restrict__ out16) {
    __shared__ __align__(16) char tb[32768];
    int wid = threadIdx.x >> 6, lane = threadIdx.x & 63, lrow = lane & 15, lq = lane >> 4;
    int wm = wid >> 2, wn = wid & 3;
    int rowbase = blockIdx.x * 128;
    // stage gathered rows once per block
    {
        int srow = threadIdx.x >> 2, sseg = threadIdx.x & 3;
        int nb = idx[rowbase + srow];
        const bfrag* src = (const bfrag*)(fin16 + (size_t)nb * 128);
        #pragma unroll
        for (int j = 0; j < 4; ++j) {
            int seg = sseg + j * 4;
            bfrag v = src[seg];
            *(bfrag*)(tb + swz(srow, seg * 16)) = v;
        }
    }
    __syncthreads();
    float bb1[2], bb2[2];
    #pragma unroll
    for (int ct = 0; ct < 2; ++ct) {
        bb1[ct] = b1[wn * 32 + ct * 16 + lrow];
        bb2[ct] = b2[wn * 32 + ct * 16 + lrow];
    }
    f32x4 zv = {0.f, 0.f, 0.f, 0.f};
    f32x4 acc[4][2];
    #pragma unroll
    for (int rt = 0; rt < 4; ++rt) { acc[rt][0] = zv; acc[rt][1] = zv; }
    const bfrag* bp1 = (const bfrag*)w1p;
    #pragma unroll
    for (int s = 0; s < 4; ++s) {
        bfrag Bv[2];
        #pragma unroll
        for (int ct = 0; ct < 2; ++ct) Bv[ct] = bp1[(s * 8 + wn * 2 + ct) * 64 + lane];
        bfrag av[4];
        #pragma unroll
        for (int rt = 0; rt < 4; ++rt) {
            int row = wm * 64 + rt * 16 + lrow;
            av[rt] = *(const bfrag*)(tb + swz(row, s * 64 + lq * 16));
        }
        #pragma unroll
        for (int ct = 0; ct < 2; ++ct)
            #pragma unroll
            for (int rt = 0; rt < 4; ++rt) acc[rt][ct] = MFMA(av[rt], Bv[ct], acc[rt][ct]);
    }
    {   // k-step 4: xyz concat (cols 128..130)
        bfrag Bv[2];
        #pragma unroll
        for (int ct = 0; ct < 2; ++ct) Bv[ct] = bp1[(32 + wn * 2 + ct) * 64 + lane];
        bfrag av[4];
        #pragma unroll
        for (int rt = 0; rt < 4; ++rt) {
            #pragma unroll
            for (int r = 0; r < 8; ++r) av[rt][r] = 0;
            if (lq == 0) {
                int gr = rowbase + wm * 64 + rt * 16 + lrow;
                av[rt][0] = f2b(xyz[gr * 3]); av[rt][1] = f2b(xyz[gr * 3 + 1]); av[rt][2] = f2b(xyz[gr * 3 + 2]);
            }
        }
        #pragma unroll
        for (int ct = 0; ct < 2; ++ct)
            #pragma unroll
            for (int rt = 0; rt < 4; ++rt) acc[rt][ct] = MFMA(av[rt], Bv[ct], acc[rt][ct]);
    }
    __syncthreads();   // all GEMM1 reads of tb done before overwrite
    #pragma unroll
    for (int rt = 0; rt < 4; ++rt)
        #pragma unroll
        for (int ct = 0; ct < 2; ++ct)
            #pragma unroll
            for (int r = 0; r < 4; ++r) {
                int row = wm * 64 + rt * 16 + lq * 4 + r, col = wn * 32 + ct * 16 + lrow;
                *(short*)(tb + swz(row, col * 2)) = f2b(lrelu(acc[rt][ct][r] + bb1[ct]));
            }
    __syncthreads();
    f32x4 acc2[4][2];
    #pragma unroll
    for (int rt = 0; rt < 4; ++rt) { acc2[rt][0] = zv; acc2[rt][1] = zv; }
    const bfrag* bp2 = (const bfrag*)w2p;
    #pragma unroll
    for (int s = 0; s < 4; ++s) {
        bfrag Bv[2];
        #pragma unroll
        for (int ct = 0; ct < 2; ++ct) Bv[ct] = bp2[(s * 8 + wn * 2 + ct) * 64 + lane];
        bfrag av[4];
        #pragma unroll
        for (int rt = 0; rt < 4; ++rt) {
            int row = wm * 64 + rt * 16 + lrow;
            av[rt] = *(const bfrag*)(tb + swz(row, s * 64 + lq * 16));
        }
        #pragma unroll
        for (int ct = 0; ct < 2; ++ct)
            #pragma unroll
            for (int rt = 0; rt < 4; ++rt) acc2[rt][ct] = MFMA(av[rt], Bv[ct], acc2[rt][ct]);
    }
    #pragma unroll
    for (int rt = 0; rt < 4; ++rt)
        #pragma unroll
        for (int ct = 0; ct < 2; ++ct) {
            float m = -INFINITY;
            #pragma unroll
            for (int r = 0; r < 4; ++r) m = fmaxf(m, acc2[rt][ct][r] + bb2[ct]);
            m = fmaxf(m, __shfl_xor(m, 16, 64));
            if ((lq & 1) == 0) {
                int p = (rowbase >> 3) + wm * 8 + rt * 2 + (lq >> 1);
                float v = lrelu(m);
                out32[(size_t)p * 128 + wn * 32 + ct * 16 + lrow] = v;
                out16[(size_t)p * 128 + wn * 32 + ct * 16 + lrow] = f2b(v);
            }
        }
}

// ---------------- pc_res: block M64, grid 2x/CU ----------------
__global__ __launch_bounds__(512) void k_pcres(
    const float* __restrict__ fin32, const short* __restrict__ fin16,
    const short* __restrict__ w1p, const float* __restrict__ b1,
    const short* __restrict__ w2p, const float* __restrict__ b2,
    float* __restrict__ out32, short* __restrict__ out16) {
    __shared__ __align__(16) char tb[16384];
    int wid = threadIdx.x >> 6, lane = threadIdx.x & 63, lrow = lane & 15, lq = lane >> 4;
    int wm = wid >> 2, wn = wid & 3;
    int rowbase = blockIdx.x * 64;
    float bb1[2], bb2[2];
    #pragma unroll
    for (int ct = 0; ct < 2; ++ct) {
        bb1[ct] = b1[wn * 32 + ct * 16 + lrow];
        bb2[ct] = b2[wn * 32 + ct * 16 + lrow];
    }
    f32x4 zv = {0.f, 0.f, 0.f, 0.f};
    f32x4 acc[2][2];
    #pragma unroll
    for (int rt = 0; rt < 2; ++rt) { acc[rt][0] = zv; acc[rt][1] = zv; }
    const bfrag* bp1 = (const bfrag*)w1p;
    #pragma unroll
    for (int s = 0; s < 4; ++s) {
        bfrag Bv[2];
        #pragma unroll
        for (int ct = 0; ct < 2; ++ct) Bv[ct] = bp1[(s * 8 + wn * 2 + ct) * 64 + lane];
        bfrag av[2];
        #pragma unroll
        for (int rt = 0; rt < 2; ++rt)
            av[rt] = *((const bfrag*)(fin16 + (size_t)(rowbase + wm * 32 + rt * 16 + lrow) * 128) + s * 4 + lq);
        #pragma unroll
        for (int ct = 0; ct < 2; ++ct)
            #pragma unroll
            for (int rt = 0; rt < 2; ++rt) acc[rt][ct] = MFMA(av[rt], Bv[ct], acc[rt][ct]);
    }
    #pragma unroll
    for (int rt = 0; rt < 2; ++rt)
        #pragma unroll
        for (int ct = 0; ct < 2; ++ct)
            #pragma unroll
            for (int r = 0; r < 4; ++r) {
                int row = wm * 32 + rt * 16 + lq * 4 + r, col = wn * 32 + ct * 16 + lrow;
                *(short*)(tb + swz(row, col * 2)) = f2b(lrelu(acc[rt][ct][r] + bb1[ct]));
            }
    __syncthreads();
    f32x4 acc2[2][2];
    #pragma unroll
    for (int rt = 0; rt < 2; ++rt) { acc2[rt][0] = zv; acc2[rt][1] = zv; }
    const bfrag* bp2 = (const bfrag*)w2p;
    #pragma unroll
    for (int s = 0; s < 4; ++s) {
        bfrag Bv[2];
        #pragma unroll
        for (int ct = 0; ct < 2; ++ct) Bv[ct] = bp2[(s * 8 + wn * 2 + ct) * 64 + lane];
        bfrag av[2];
        #pragma unroll
        for (int rt = 0; rt < 2; ++rt) {
            int row = wm * 32 + rt * 16 + lrow;
            av[rt] = *(const bfrag*)(tb + swz(row, s * 64 + lq * 16));
        }
        #pragma unroll
        for (int ct = 0; ct < 2; ++ct)
            #pragma unroll
            for (int rt = 0; rt < 2; ++rt) acc2[rt][ct] = MFMA(av[rt], Bv[ct], acc2[rt][ct]);
    }
    #pragma unroll
    for (int rt = 0; rt < 2; ++rt)
        #pragma unroll
        for (int ct = 0; ct < 2; ++ct)
            #pragma unroll
            for (int r = 0; r < 4; ++r) {
                int row = wm * 32 + rt * 16 + lq * 4 + r, col = wn * 32 + ct * 16 + lrow;
                size_t o = (size_t)(rowbase + row) * 128 + col;
                float v = lrelu(acc2[rt][ct][r] + bb2[ct] + fin32[o]);
                out32[o] = v; out16[o] = f2b(v);
            }
}

// ---------------- conv3d 3x3x3: dbuf LDS A-staging + reg B-prefetch; fused 1x1 + residual ----------------
__global__ __launch_bounds__(512) void k_conv3(
    const float* __restrict__ gin32, const short* __restrict__ gin16,
    const short* __restrict__ w1p, const float* __restrict__ b1,
    const short* __restrict__ w2p, const float* __restrict__ b2,
    float* __restrict__ gout32, short* __restrict__ gout16) {
    __shared__ __align__(16) char Ab[2][32768];
    int wid = threadIdx.x >> 6, lane = threadIdx.x & 63, lrow = lane & 15, lq = lane >> 4;
    int wm = wid >> 2, wn = wid & 3;
    int va = blockIdx.x >> 3, vb0 = (blockIdx.x & 7) * 4;
    int srow = threadIdx.x >> 2, sseg = threadIdx.x & 3;
    int sb = srow >> 5, sc = srow & 31;                 // staging row -> (b-line, c)
    bfrag zf;
    #pragma unroll
    for (int r = 0; r < 8; ++r) zf[r] = 0;
    float bb1[2], bb2[2];
    #pragma unroll
    for (int ct = 0; ct < 2; ++ct) {
        bb1[ct] = b1[wn * 32 + ct * 16 + lrow];
        bb2[ct] = b2[wn * 32 + ct * 16 + lrow];
    }
    f32x4 zv = {0.f, 0.f, 0.f, 0.f};
    f32x4 acc[4][2];
    #pragma unroll
    for (int rt = 0; rt < 4; ++rt) { acc[rt][0] = zv; acc[rt][1] = zv; }
    const bfrag* bp1 = (const bfrag*)w1p;

    // prologue: stage tap 0 into Ab[0]; load tap-0 B into regs
    bfrag Bcur[8];
    #pragma unroll
    for (int s = 0; s < 4; ++s)
        #pragma unroll
        for (int ct = 0; ct < 2; ++ct) Bcur[s * 2 + ct] = bp1[(s * 8 + wn * 2 + ct) * 64 + lane];
    {
        int aa = va - 1, bb = vb0 + sb - 1, cc = sc - 1;
        bool ok = ((unsigned)aa < 32u) && ((unsigned)bb < 32u) && ((unsigned)cc < 32u);
        int soff = ok ? ((aa * 32 + bb) * 32 + cc) * 128 : 0;
        const bfrag* src = (const bfrag*)(gin16 + soff);
        #pragma unroll
        for (int j = 0; j < 4; ++j) {
            int seg = sseg + j * 4;
            bfrag v = src[seg];
            *(bfrag*)(Ab[0] + swz(srow, seg * 16)) = ok ? v : zf;
        }
    }
    __syncthreads();

    #pragma unroll 1
    for (int tap = 0; tap < 27; ++tap) {
        // issue next-tap A-stage loads + next-tap B prefetch (hide under this tap's MFMA)
        bfrag st[4];
        bool okn = false;
        bfrag Bnxt[8];
        if (tap < 26) {
            int tn = tap + 1;
            int da = tn / 9 - 1, db = (tn / 3) % 3 - 1, dc = tn % 3 - 1;
            int aa = va + da, bb = vb0 + sb + db, cc = sc + dc;
            okn = ((unsigned)aa < 32u) && ((unsigned)bb < 32u) && ((unsigned)cc < 32u);
            int soff = okn ? ((aa * 32 + bb) * 32 + cc) * 128 : 0;
            const bfrag* src = (const bfrag*)(gin16 + soff);
            #pragma unroll
            for (int j = 0; j < 4; ++j) st[j] = src[sseg + j * 4];
            #pragma unroll
            for (int s = 0; s < 4; ++s)
                #pragma unroll
                for (int ct = 0; ct < 2; ++ct)
                    Bnxt[s * 2 + ct] = bp1[((tn * 4 + s) * 8 + wn * 2 + ct) * 64 + lane];
        }
        // compute current tap from Ab[tap&1] using Bcur
        const char* tbc = Ab[tap & 1];
        #pragma unroll
        for (int s = 0; s < 4; ++s) {
            bfrag av[4];
            #pragma unroll
            for (int rt = 0; rt < 4; ++rt) {
                int row = wm * 64 + rt * 16 + lrow;
                av[rt] = *(const bfrag*)(tbc + swz(row, s * 64 + lq * 16));
            }
            #pragma unroll
            for (int ct = 0; ct < 2; ++ct)
                #pragma unroll
                for (int rt = 0; rt < 4; ++rt) acc[rt][ct] = MFMA(av[rt], Bcur[s * 2 + ct], acc[rt][ct]);
        }
        // write staged rows into the other buffer; rotate B regs
        if (tap < 26) {
            char* nb = Ab[(tap + 1) & 1];
            #pragma unroll
            for (int j = 0; j < 4; ++j)
                *(bfrag*)(nb + swz(srow, (sseg + j * 4) * 16)) = okn ? st[j] : zf;
            #pragma unroll
            for (int i = 0; i < 8; ++i) Bcur[i] = Bnxt[i];
        }
        __syncthreads();
    }

    // epilogue: bias+lrelu -> t tile (reuse Ab[0]); then fused 1x1 + residual
    #pragma unroll
    for (int rt = 0; rt < 4; ++rt)
        #pragma unroll
        for (int ct = 0; ct < 2; ++ct)
            #pragma unroll
            for (int r = 0; r < 4; ++r) {
                int row = wm * 64 + rt * 16 + lq * 4 + r, col = wn * 32 + ct * 16 + lrow;
                *(short*)(Ab[0] + swz(row, col * 2)) = f2b(lrelu(acc[rt][ct][r] + bb1[ct]));
            }
    __syncthreads();
    f32x4 acc2[4][2];
    #pragma unroll
    for (int rt = 0; rt < 4; ++rt) { acc2[rt][0] = zv; acc2[rt][1] = zv; }
    const bfrag* bp2 = (const bfrag*)w2p;
    #pragma unroll
    for (int s = 0; s < 4; ++s) {
        bfrag Bv[2];
        #pragma unroll
        for (int ct = 0; ct < 2; ++ct) Bv[ct] = bp2[(s * 8 + wn * 2 + ct) * 64 + lane];
        bfrag av[4];
        #pragma unroll
        for (int rt = 0; rt < 4; ++rt) {
            int row = wm * 64 + rt * 16 + lrow;
            av[rt] = *(const bfrag*)(Ab[0] + swz(row, s * 64 + lq * 16));
        }
        #pragma unroll
        for (int ct = 0; ct < 2; ++ct)
            #pragma unroll
            for (int rt = 0; rt < 4; ++rt) acc2[rt][ct] = MFMA(av[rt], Bv[ct], acc2[rt][ct]);
    }
    #pragma unroll
    for (int rt = 0; rt < 4; ++rt)
        #pragma unroll
        for (int ct = 0; ct < 2; ++ct)
            #pragma unroll
            for (int r = 0; r < 4; ++r) {
                int row = wm * 64 + rt * 16 + lq * 4 + r;
                int voxel = (va * 32 + vb0 + (row >> 5)) * 32 + (row & 31);
                size_t o = (size_t)voxel * 128 + wn * 32 + ct * 16 + lrow;
                float v = lrelu(acc2[rt][ct][r] + bb2[ct] + gin32[o]);
                gout32[o] = v; gout16[o] = f2b(v);
            }
}

// ---------------- head: gather + lin1 + lin2 + linb + sigmoid; block M64, 8 waves ----------------
__global__ __launch_bounds__(512) void k_head(
    const short* __restrict__ g16, const int* __restrict__ vx, const int* __restrict__ vmin,
    const short* __restrict__ w1p, const float* __restrict__ b1,
    const short* __restrict__ w2p, const float* __restrict__ b2,
    const float* __restrict__ W3, const float* __restrict__ b3,
    float* __restrict__ out) {
    __shared__ __align__(16) char tb[16384];
    __shared__ float t2[64][129];
    int wid = threadIdx.x >> 6, lane = threadIdx.x & 63, lrow = lane & 15, lq = lane >> 4;
    int rowbase = blockIdx.x * 64;
    int goff[4];
    #pragma unroll
    for (int rt = 0; rt < 4; ++rt) {
        int m = rowbase + rt * 16 + lrow;
        int v0 = vx[m * 3 + 0] - vmin[0];
        int v1 = vx[m * 3 + 1] - vmin[1];
        int v2 = vx[m * 3 + 2] - vmin[2];
        goff[rt] = ((v0 * 32 + v1) * 32 + v2) * 128;
    }
    float bb1 = b1[wid * 16 + lrow], bb2 = b2[wid * 16 + lrow];
    f32x4 zv = {0.f, 0.f, 0.f, 0.f};
    f32x4 acc[4];
    #pragma unroll
    for (int rt = 0; rt < 4; ++rt) acc[rt] = zv;
    const bfrag* bp1 = (const bfrag*)w1p;
    #pragma unroll
    for (int s = 0; s < 4; ++s) {
        bfrag B = bp1[(s * 8 + wid) * 64 + lane];
        #pragma unroll
        for (int rt = 0; rt < 4; ++rt) {
            bfrag a = *((const bfrag*)(g16 + goff[rt]) + s * 4 + lq);
            acc[rt] = MFMA(a, B, acc[rt]);
        }
    }
    #pragma unroll
    for (int rt = 0; rt < 4; ++rt)
        #pragma unroll
        for (int r = 0; r < 4; ++r) {
            int row = rt * 16 + lq * 4 + r, col = wid * 16 + lrow;
            *(short*)(tb + swz(row, col * 2)) = f2b(lrelu(acc[rt][r] + bb1));
        }
    __syncthreads();
    f32x4 acc2[4];
    #pragma unroll
    for (int rt = 0; rt < 4; ++rt) acc2[rt] = zv;
    const bfrag* bp2 = (const bfrag*)w2p;
    #pragma unroll
    for (int s = 0; s < 4; ++s) {
        bfrag B = bp2[(s * 8 + wid) * 64 + lane];
        #pragma unroll
        for (int rt = 0; rt < 4; ++rt) {
            int row = rt * 16 + lrow;
            bfrag av = *(const bfrag*)(tb + swz(row, s * 64 + lq * 16));
            acc2[rt] = MFMA(av, B, acc2[rt]);
        }
    }
    #pragma unroll
    for (int rt = 0; rt < 4; ++rt)
        #pragma unroll
        for (int r = 0; r < 4; ++r) {
            int row = rt * 16 + lq * 4 + r, col = wid * 16 + lrow;
            t2[row][col] = lrelu(acc2[rt][r] + bb2);
        }
    __syncthreads();
    if (threadIdx.x < 192) {
        int row = threadIdx.x & 63, c = threadIdx.x >> 6;
        float s = b3[c];
        #pragma unroll 4
        for (int k = 0; k < 128; ++k) s += t2[row][k] * W3[k * 3 + c];
        out[(size_t)(rowbase + row) * 3 + c] = 1.f / (1.f + expf(-s));
    }
}

// ---------------- small kernels ----------------
__global__ void k_vmin(const int* __restrict__ vx, int M, int* __restrict__ vmin) {
    __shared__ int sm[3 * 256];
    int t = threadIdx.x;
    int m0 = 0x7fffffff, m1 = 0x7fffffff, m2 = 0x7fffffff;
    for (int i = t; i < M; i += 256) {
        m0 = min(m0, vx[i * 3 + 0]); m1 = min(m1, vx[i * 3 + 1]); m2 = min(m2, vx[i * 3 + 2]);
    }
    sm[t] = m0; sm[256 + t] = m1; sm[512 + t] = m2;
    __syncthreads();
    for (int s = 128; s > 0; s >>= 1) {
        if (t < s) {
            sm[t] = min(sm[t], sm[t + s]);
            sm[256 + t] = min(sm[256 + t], sm[256 + t + s]);
            sm[512 + t] = min(sm[512 + t], sm[512 + t + s]);
        }
        __syncthreads();
    }
    if (t == 0) { vmin[0] = sm[0]; vmin[1] = sm[256]; vmin[2] = sm[512]; }
}

__global__ void k_scatter(const float* __restrict__ vf, const int* __restrict__ vx,
                          const int* __restrict__ vmin, float* __restrict__ g32, short* __restrict__ g16) {
    int m = blockIdx.x, j = threadIdx.x;
    int v0 = vx[m * 3 + 0] - vmin[0];
    int v1 = vx[m * 3 + 1] - vmin[1];
    int v2 = vx[m * 3 + 2] - vmin[2];
    size_t o = (size_t)(((v0 * GDIM) + v1) * GDIM + v2) * EF + j;
    float v = vf[(size_t)m * EF + j];
    g32[o] = v; g16[o] = f2b(v);
}

extern "C" void kernel_launch(void* const* d_in, const int* in_sizes, int n_in,
                              void* d_out, int out_size, void* d_ws, size_t ws_size,
                              hipStream_t stream) {
    const int*   pc_idx  = (const int*)  d_in[0];
    const float* pc_xyz  = (const float*)d_in[1];
    const int*   vox_int = (const int*)  d_in[2];
    const int*   vox_idx = (const int*)  d_in[3];
    const float* vox_xyz = (const float*)d_in[4];
    const float* pcf_W1  = (const float*)d_in[5];
    const float* pcf_b1  = (const float*)d_in[6];
    const float* pcf_W2  = (const float*)d_in[7];
    const float* pcf_b2  = (const float*)d_in[8];
    const float* pcres_W1 = (const float*)d_in[9];
    const float* pcres_b1 = (const float*)d_in[10];
    const float* pcres_W2 = (const float*)d_in[11];
    const float* pcres_b2 = (const float*)d_in[12];
    const float* pcc_W1  = (const float*)d_in[13];
    const float* pcc_b1  = (const float*)d_in[14];
    const float* pcc_W2  = (const float*)d_in[15];
    const float* pcc_b2  = (const float*)d_in[16];
    const float* r3_Wc1  = (const float*)d_in[17];
    const float* r3_bc1  = (const float*)d_in[18];
    const float* r3_Wc2  = (const float*)d_in[19];
    const float* r3_bc2  = (const float*)d_in[20];
    const float* lin1_W  = (const float*)d_in[21];
    const float* lin1_b  = (const float*)d_in[22];
    const float* lin2_W  = (const float*)d_in[23];
    const float* lin2_b  = (const float*)d_in[24];
    const float* linb_W  = (const float*)d_in[25];
    const float* linb_b  = (const float*)d_in[26];

    const size_t NE = (size_t)NPTS * EF;   // 4M elements
    float* A32 = (float*)d_ws;
    float* B32 = A32 + NE;
    short* A16 = (short*)(B32 + NE);
    short* B16 = A16 + NE;
    float* Y32 = (float*)(B16 + NE);
    short* Y16 = (short*)(Y32 + NE);
    short* pcf_w2p = Y16 + NE;
    short* pcc_w1p = pcf_w2p + 4 * 4096;       // 6 layers x 5 steps
    short* pcc_w2p = pcc_w1p + 6 * 5 * 4096;   // 6 x 4
    short* pcr_w1p = pcc_w2p + 6 * 4 * 4096;   // 7 x 4
    short* pcr_w2p = pcr_w1p + 7 * 4 * 4096;
    short* wc2p    = pcr_w2p + 7 * 4 * 4096;   // 8 x 4
    short* lin1p   = wc2p    + 8 * 4 * 4096;
    short* lin2p   = lin1p   + 4 * 4096;
    short* wc1p    = lin2p   + 4 * 4096;       // 108 steps (one layer at a time)
    int*   vmin    = (int*)(wc1p + 108 * 4096);

    // ---- pack weights ----
    k_pack_w<<<64, 256, 0, stream>>>(pcf_W2, pcf_w2p, 128, 4, 128, 1);
    for (int i = 0; i < 6; ++i) {
        k_pack_w<<<80, 256, 0, stream>>>(pcc_W1 + (size_t)i * 131 * 128, pcc_w1p + (size_t)i * 5 * 4096, 131, 5, 128, 1);
        k_pack_w<<<64, 256, 0, stream>>>(pcc_W2 + (size_t)i * 128 * 128, pcc_w2p + (size_t)i * 4 * 4096, 128, 4, 128, 1);
    }
    for (int i = 0; i < 7; ++i) {
        k_pack_w<<<64, 256, 0, stream>>>(pcres_W1 + (size_t)i * 128 * 128, pcr_w1p + (size_t)i * 4 * 4096, 128, 4, 128, 1);
        k_pack_w<<<64, 256, 0, stream>>>(pcres_W2 + (size_t)i * 128 * 128, pcr_w2p + (size_t)i * 4 * 4096, 128, 4, 128, 1);
    }
    for (int i = 0; i < 8; ++i)
        k_pack_w<<<64, 256, 0, stream>>>(r3_Wc2 + (size_t)i * 128 * 128, wc2p + (size_t)i * 4 * 4096, 128, 4, 1, 128);
    k_pack_w<<<64, 256, 0, stream>>>(lin1_W, lin1p, 128, 4, 128, 1);
    k_pack_w<<<64, 256, 0, stream>>>(lin2_W, lin2p, 128, 4, 128, 1);

    // ---- point-cloud stack (A/B ping-pong; fp32 master + bf16 mirror) ----
    k_pcfirst<<<NPTS * KNN / 128, 512, 0, stream>>>(pc_xyz, pcf_W1, pcf_b1, pcf_w2p, pcf_b2, A32, A16);
    k_pcres<<<NPTS / 64, 512, 0, stream>>>(A32, A16, pcr_w1p, pcres_b1, pcr_w2p, pcres_b2, B32, B16);
    for (int i = 0; i < 5; ++i) {
        k_pcconv<<<NPTS * KNN / 128, 512, 0, stream>>>(B16, pc_idx, pc_xyz,
            pcc_w1p + (size_t)i * 5 * 4096, pcc_b1 + i * EF,
            pcc_w2p + (size_t)i * 4 * 4096, pcc_b2 + i * EF, A32, A16);
        k_pcres<<<NPTS / 64, 512, 0, stream>>>(A32, A16,
            pcr_w1p + (size_t)(i + 1) * 4 * 4096, pcres_b1 + (i + 1) * EF,
            pcr_w2p + (size_t)(i + 1) * 4 * 4096, pcres_b2 + (i + 1) * EF, B32, B16);
    }
    k_pcconv<<<MVOX * KNN / 128, 512, 0, stream>>>(B16, vox_idx, vox_xyz,
        pcc_w1p + (size_t)5 * 5 * 4096, pcc_b1 + 5 * EF,
        pcc_w2p + (size_t)5 * 4 * 4096, pcc_b2 + 5 * EF, A32, A16);
    k_pcres<<<MVOX / 64, 512, 0, stream>>>(A32, A16,
        pcr_w1p + (size_t)6 * 4 * 4096, pcres_b1 + 6 * EF,
        pcr_w2p + (size_t)6 * 4 * 4096, pcres_b2 + 6 * EF, B32, B16);
    // voxfeat now in B32 (rows 0..MVOX-1); A buffers dead -> reuse as grid X

    k_vmin<<<1, 256, 0, stream>>>(vox_int, MVOX, vmin);
    hipMemsetAsync(A32, 0, NE * sizeof(float), stream);
    hipMemsetAsync(A16, 0, NE * sizeof(short), stream);
    k_scatter<<<MVOX, 128, 0, stream>>>(B32, vox_int, vmin, A32, A16);

    // ---- 8 x resnet_block_rec3 (ping-pong A <-> Y) ----
    float* cur32 = A32; short* cur16 = A16;
    float* nxt32 = Y32; short* nxt16 = Y16;
    for (int i = 0; i < 8; ++i) {
        k_pack_wc1<<<1728, 256, 0, stream>>>(r3_Wc1 + (size_t)i * 128 * 128 * 27, wc1p);
        k_conv3<<<256, 512, 0, stream>>>(cur32, cur16, wc1p, r3_bc1 + i * EF,
                                         wc2p + (size_t)i * 4 * 4096, r3_bc2 + i * EF,
                                         nxt32, nxt16);
        float* t32 = cur32; cur32 = nxt32; nxt32 = t32;
        short* t16 = cur16; cur16 = nxt16; nxt16 = t16;
    }

    // ---- head ----
    k_head<<<MVOX / 64, 512, 0, stream>>>(cur16, vox_int, vmin,
                                          lin1p, lin1_b, lin2p, lin2_b, linb_W, linb_b,
                                          (float*)d_out);
}

// Round 7
// 747.952 us; speedup vs baseline: 3.1975x; 1.1410x over previous
//
#include <hip/hip_runtime.h>
#include <math.h>

#define EF 128
#define NPTS 32768
#define KNN 8
#define MVOX 8192
#define GDIM 32
#define NVOXG (GDIM*GDIM*GDIM)

typedef __attribute__((ext_vector_type(8))) short bfrag;   // 8 x bf16
typedef __attribute__((ext_vector_type(4))) float f32x4;

__device__ __forceinline__ float lrelu(float x) { return x > 0.f ? x : 0.01f * x; }
__device__ __forceinline__ short f2b(float f) {            // fp32 -> bf16 (RNE)
    unsigned u = __float_as_uint(f);
    return (short)((u + 0x7fff + ((u >> 16) & 1)) >> 16);
}
#define MFMA(a,b,c) __builtin_amdgcn_mfma_f32_16x16x32_bf16((a),(b),(c),0,0,0)
// LDS tile addressing: row-major 256B rows, XOR swizzle on byte bits 4-6
__device__ __forceinline__ int swz(int row, int bytecol) {
    return row * 256 + (bytecol ^ ((row & 7) << 4));
}

// ---------------- weight packing: W[k][col] (strided) -> [step][ct][lane][8] bf16 ----------------
__global__ void k_pack_w(const float* __restrict__ src, short* __restrict__ dst,
                         int K_real, int n_steps, int k_str, int c_str) {
    int t = blockIdx.x * 256 + threadIdx.x;
    int total = n_steps * 4096;
    if (t >= total) return;
    int r = t & 7, l = (t >> 3) & 63, ct = (t >> 9) & 7, s = t >> 12;
    int k = s * 32 + (l >> 4) * 8 + r;
    int col = ct * 16 + (l & 15);
    float v = (k < K_real) ? src[(size_t)k * k_str + (size_t)col * c_str] : 0.f;
    dst[t] = f2b(v);
}
// conv3x3x3 weights [o][ci][27] -> [tap*4+cc][ct][lane][8]
__global__ void k_pack_wc1(const float* __restrict__ src, short* __restrict__ dst) {
    int t = blockIdx.x * 256 + threadIdx.x;
    if (t >= 108 * 4096) return;
    int r = t & 7, l = (t >> 3) & 63, ct = (t >> 9) & 7, s = t >> 12;
    int tap = s >> 2;
    int ci = (s & 3) * 32 + (l >> 4) * 8 + r;
    int col = ct * 16 + (l & 15);
    dst[t] = f2b(src[((size_t)col * 128 + ci) * 27 + tap]);
}

// ============ template: block = 128 gather-rows (16 out rows), 8 waves 2Mx4N, fused res ============

// ---------------- pc_conv_first: MFMA phase-1 + GEMM2 + pool + fused res0 ----------------
__global__ __launch_bounds__(512) void k_pcfirst(
    const float* __restrict__ xyz, const short* __restrict__ w1p, const float* __restrict__ b1,
    const short* __restrict__ w2p, const float* __restrict__ b2,
    const short* __restrict__ rw1p, const float* __restrict__ rb1,
    const short* __restrict__ rw2p, const float* __restrict__ rb2,
    float* __restrict__ out32, short* __restrict__ out16) {
    __shared__ __align__(16) char tb[32768];
    int wid = threadIdx.x >> 6, lane = threadIdx.x & 63, lrow = lane & 15, lq = lane >> 4;
    int wm = wid >> 2, wn = wid & 3;
    int rowbase = blockIdx.x * 128;
    f32x4 zv = {0.f, 0.f, 0.f, 0.f};
    // ---- phase 1: 3->128 via 1-k-step MFMA ----
    {
        f32x4 acc1[4][2];
        #pragma unroll
        for (int rt = 0; rt < 4; ++rt) { acc1[rt][0] = zv; acc1[rt][1] = zv; }
        bfrag Bv[2];
        #pragma unroll
        for (int ct = 0; ct < 2; ++ct) Bv[ct] = ((const bfrag*)w1p)[(wn * 2 + ct) * 64 + lane];
        #pragma unroll
        for (int rt = 0; rt < 4; ++rt) {
            bfrag a4;
            #pragma unroll
            for (int r = 0; r < 8; ++r) a4[r] = 0;
            if (lq == 0) {
                int gr = rowbase + wm * 64 + rt * 16 + lrow;
                a4[0] = f2b(xyz[gr * 3]); a4[1] = f2b(xyz[gr * 3 + 1]); a4[2] = f2b(xyz[gr * 3 + 2]);
            }
            #pragma unroll
            for (int ct = 0; ct < 2; ++ct) acc1[rt][ct] = MFMA(a4, Bv[ct], acc1[rt][ct]);
        }
        float bb1[2];
        #pragma unroll
        for (int ct = 0; ct < 2; ++ct) bb1[ct] = b1[wn * 32 + ct * 16 + lrow];
        #pragma unroll
        for (int rt = 0; rt < 4; ++rt)
            #pragma unroll
            for (int ct = 0; ct < 2; ++ct)
                #pragma unroll
                for (int r = 0; r < 4; ++r) {
                    int row = wm * 64 + rt * 16 + lq * 4 + r, col = wn * 32 + ct * 16 + lrow;
                    *(short*)(tb + swz(row, col * 2)) = f2b(lrelu(acc1[rt][ct][r] + bb1[ct]));
                }
    }
    __syncthreads();
    // ---- GEMM2 + pool ----
    float bb2[2];
    #pragma unroll
    for (int ct = 0; ct < 2; ++ct) bb2[ct] = b2[wn * 32 + ct * 16 + lrow];
    f32x4 acc[4][2];
    #pragma unroll
    for (int rt = 0; rt < 4; ++rt) { acc[rt][0] = zv; acc[rt][1] = zv; }
    const bfrag* bp2 = (const bfrag*)w2p;
    #pragma unroll
    for (int s = 0; s < 4; ++s) {
        bfrag Bv[2];
        #pragma unroll
        for (int ct = 0; ct < 2; ++ct) Bv[ct] = bp2[(s * 8 + wn * 2 + ct) * 64 + lane];
        bfrag av[4];
        #pragma unroll
        for (int rt = 0; rt < 4; ++rt) {
            int row = wm * 64 + rt * 16 + lrow;
            av[rt] = *(const bfrag*)(tb + swz(row, s * 64 + lq * 16));
        }
        #pragma unroll
        for (int ct = 0; ct < 2; ++ct)
            #pragma unroll
            for (int rt = 0; rt < 4; ++rt) acc[rt][ct] = MFMA(av[rt], Bv[ct], acc[rt][ct]);
    }
    float pv[4][2];
    #pragma unroll
    for (int rt = 0; rt < 4; ++rt)
        #pragma unroll
        for (int ct = 0; ct < 2; ++ct) {
            float m = -INFINITY;
            #pragma unroll
            for (int r = 0; r < 4; ++r) m = fmaxf(m, acc[rt][ct][r] + bb2[ct]);
            m = fmaxf(m, __shfl_xor(m, 16, 64));
            pv[rt][ct] = lrelu(m);
        }
    // ---- pooled x -> LDS tiles ----
    __syncthreads();
    float* xf = (float*)(tb + 4096);            // [16][130]
    char*  tres = tb + 12544;                   // 16-row swizzled bf16 tile
    if ((lq & 1) == 0) {
        #pragma unroll
        for (int rt = 0; rt < 4; ++rt)
            #pragma unroll
            for (int ct = 0; ct < 2; ++ct) {
                int row = wm * 8 + rt * 2 + (lq >> 1), col = wn * 32 + ct * 16 + lrow;
                *(short*)(tb + swz(row, col * 2)) = f2b(pv[rt][ct]);
                xf[row * 130 + col] = pv[rt][ct];
            }
    }
    __syncthreads();
    // ---- fused res: GEMM1 ----
    {
        f32x4 r1 = zv;
        #pragma unroll
        for (int s = 0; s < 4; ++s) {
            bfrag B = ((const bfrag*)rw1p)[(s * 8 + wid) * 64 + lane];
            bfrag a = *(const bfrag*)(tb + swz(lrow, s * 64 + lq * 16));
            r1 = MFMA(a, B, r1);
        }
        float rb1v = rb1[wid * 16 + lrow];
        #pragma unroll
        for (int r = 0; r < 4; ++r) {
            int row = lq * 4 + r;
            *(short*)(tres + swz(row, (wid * 16 + lrow) * 2)) = f2b(lrelu(r1[r] + rb1v));
        }
    }
    __syncthreads();
    {
        f32x4 r2 = zv;
        #pragma unroll
        for (int s = 0; s < 4; ++s) {
            bfrag B = ((const bfrag*)rw2p)[(s * 8 + wid) * 64 + lane];
            bfrag a = *(const bfrag*)(tres + swz(lrow, s * 64 + lq * 16));
            r2 = MFMA(a, B, r2);
        }
        float rb2v = rb2[wid * 16 + lrow];
        int p0 = blockIdx.x * 16;
        #pragma unroll
        for (int r = 0; r < 4; ++r) {
            int row = lq * 4 + r, col = wid * 16 + lrow;
            float v = lrelu(r2[r] + rb2v + xf[row * 130 + col]);
            size_t o = (size_t)(p0 + row) * 128 + col;
            out16[o] = f2b(v);
            if (out32) out32[o] = v;
        }
    }
}

// ---------------- pc_conv: staged gather + 131->128 + 128->128 + pool + fused res ----------------
__global__ __launch_bounds__(512) void k_pcconv(
    const short* __restrict__ fin16, const int* __restrict__ idx, const float* __restrict__ xyz,
    const short* __restrict__ w1p, const float* __restrict__ b1,
    const short* __restrict__ w2p, const float* __restrict__ b2,
    const short* __restrict__ rw1p, const float* __restrict__ rb1,
    const short* __restrict__ rw2p, const float* __restrict__ rb2,
    float* __restrict__ out32, short* __restrict__ out16) {
    __shared__ __align__(16) char tb[32768];
    int wid = threadIdx.x >> 6, lane = threadIdx.x & 63, lrow = lane & 15, lq = lane >> 4;
    int wm = wid >> 2, wn = wid & 3;
    int rowbase = blockIdx.x * 128;
    f32x4 zv = {0.f, 0.f, 0.f, 0.f};
    // stage gathered rows once per block
    {
        int srow = threadIdx.x >> 2, sseg = threadIdx.x & 3;
        int nb = idx[rowbase + srow];
        const bfrag* src = (const bfrag*)(fin16 + (size_t)nb * 128);
        #pragma unroll
        for (int j = 0; j < 4; ++j) {
            int seg = sseg + j * 4;
            bfrag v = src[seg];
            *(bfrag*)(tb + swz(srow, seg * 16)) = v;
        }
    }
    __syncthreads();
    float bb1[2], bb2[2];
    #pragma unroll
    for (int ct = 0; ct < 2; ++ct) {
        bb1[ct] = b1[wn * 32 + ct * 16 + lrow];
        bb2[ct] = b2[wn * 32 + ct * 16 + lrow];
    }
    f32x4 acc[4][2];
    #pragma unroll
    for (int rt = 0; rt < 4; ++rt) { acc[rt][0] = zv; acc[rt][1] = zv; }
    const bfrag* bp1 = (const bfrag*)w1p;
    #pragma unroll
    for (int s = 0; s < 4; ++s) {
        bfrag Bv[2];
        #pragma unroll
        for (int ct = 0; ct < 2; ++ct) Bv[ct] = bp1[(s * 8 + wn * 2 + ct) * 64 + lane];
        bfrag av[4];
        #pragma unroll
        for (int rt = 0; rt < 4; ++rt) {
            int row = wm * 64 + rt * 16 + lrow;
            av[rt] = *(const bfrag*)(tb + swz(row, s * 64 + lq * 16));
        }
        #pragma unroll
        for (int ct = 0; ct < 2; ++ct)
            #pragma unroll
            for (int rt = 0; rt < 4; ++rt) acc[rt][ct] = MFMA(av[rt], Bv[ct], acc[rt][ct]);
    }
    {   // k-step 4: xyz concat (cols 128..130)
        bfrag Bv[2];
        #pragma unroll
        for (int ct = 0; ct < 2; ++ct) Bv[ct] = bp1[(32 + wn * 2 + ct) * 64 + lane];
        #pragma unroll
        for (int rt = 0; rt < 4; ++rt) {
            bfrag a4;
            #pragma unroll
            for (int r = 0; r < 8; ++r) a4[r] = 0;
            if (lq == 0) {
                int gr = rowbase + wm * 64 + rt * 16 + lrow;
                a4[0] = f2b(xyz[gr * 3]); a4[1] = f2b(xyz[gr * 3 + 1]); a4[2] = f2b(xyz[gr * 3 + 2]);
            }
            #pragma unroll
            for (int ct = 0; ct < 2; ++ct) acc[rt][ct] = MFMA(a4, Bv[ct], acc[rt][ct]);
        }
    }
    __syncthreads();   // all GEMM1 reads of tb done before overwrite
    #pragma unroll
    for (int rt = 0; rt < 4; ++rt)
        #pragma unroll
        for (int ct = 0; ct < 2; ++ct)
            #pragma unroll
            for (int r = 0; r < 4; ++r) {
                int row = wm * 64 + rt * 16 + lq * 4 + r, col = wn * 32 + ct * 16 + lrow;
                *(short*)(tb + swz(row, col * 2)) = f2b(lrelu(acc[rt][ct][r] + bb1[ct]));
            }
    __syncthreads();
    f32x4 acc2[4][2];
    #pragma unroll
    for (int rt = 0; rt < 4; ++rt) { acc2[rt][0] = zv; acc2[rt][1] = zv; }
    const bfrag* bp2 = (const bfrag*)w2p;
    #pragma unroll
    for (int s = 0; s < 4; ++s) {
        bfrag Bv[2];
        #pragma unroll
        for (int ct = 0; ct < 2; ++ct) Bv[ct] = bp2[(s * 8 + wn * 2 + ct) * 64 + lane];
        bfrag av[4];
        #pragma unroll
        for (int rt = 0; rt < 4; ++rt) {
            int row = wm * 64 + rt * 16 + lrow;
            av[rt] = *(const bfrag*)(tb + swz(row, s * 64 + lq * 16));
        }
        #pragma unroll
        for (int ct = 0; ct < 2; ++ct)
            #pragma unroll
            for (int rt = 0; rt < 4; ++rt) acc2[rt][ct] = MFMA(av[rt], Bv[ct], acc2[rt][ct]);
    }
    float pv[4][2];
    #pragma unroll
    for (int rt = 0; rt < 4; ++rt)
        #pragma unroll
        for (int ct = 0; ct < 2; ++ct) {
            float m = -INFINITY;
            #pragma unroll
            for (int r = 0; r < 4; ++r) m = fmaxf(m, acc2[rt][ct][r] + bb2[ct]);
            m = fmaxf(m, __shfl_xor(m, 16, 64));
            pv[rt][ct] = lrelu(m);
        }
    // ---- pooled x -> LDS tiles ----
    __syncthreads();
    float* xf = (float*)(tb + 4096);            // [16][130]
    char*  tres = tb + 12544;
    if ((lq & 1) == 0) {
        #pragma unroll
        for (int rt = 0; rt < 4; ++rt)
            #pragma unroll
            for (int ct = 0; ct < 2; ++ct) {
                int row = wm * 8 + rt * 2 + (lq >> 1), col = wn * 32 + ct * 16 + lrow;
                *(short*)(tb + swz(row, col * 2)) = f2b(pv[rt][ct]);
                xf[row * 130 + col] = pv[rt][ct];
            }
    }
    __syncthreads();
    // ---- fused res ----
    {
        f32x4 r1 = zv;
        #pragma unroll
        for (int s = 0; s < 4; ++s) {
            bfrag B = ((const bfrag*)rw1p)[(s * 8 + wid) * 64 + lane];
            bfrag a = *(const bfrag*)(tb + swz(lrow, s * 64 + lq * 16));
            r1 = MFMA(a, B, r1);
        }
        float rb1v = rb1[wid * 16 + lrow];
        #pragma unroll
        for (int r = 0; r < 4; ++r) {
            int row = lq * 4 + r;
            *(short*)(tres + swz(row, (wid * 16 + lrow) * 2)) = f2b(lrelu(r1[r] + rb1v));
        }
    }
    __syncthreads();
    {
        f32x4 r2 = zv;
        #pragma unroll
        for (int s = 0; s < 4; ++s) {
            bfrag B = ((const bfrag*)rw2p)[(s * 8 + wid) * 64 + lane];
            bfrag a = *(const bfrag*)(tres + swz(lrow, s * 64 + lq * 16));
            r2 = MFMA(a, B, r2);
        }
        float rb2v = rb2[wid * 16 + lrow];
        int p0 = blockIdx.x * 16;
        #pragma unroll
        for (int r = 0; r < 4; ++r) {
            int row = lq * 4 + r, col = wid * 16 + lrow;
            float v = lrelu(r2[r] + rb2v + xf[row * 130 + col]);
            size_t o = (size_t)(p0 + row) * 128 + col;
            out16[o] = f2b(v);
            if (out32) out32[o] = v;
        }
    }
}

// ---------------- conv3d 3x3x3: dbuf LDS A-staging + reg B-prefetch; fused 1x1 + residual ----------------
__global__ __launch_bounds__(512) void k_conv3(
    const float* __restrict__ gin32, const short* __restrict__ gin16,
    const short* __restrict__ w1p, const float* __restrict__ b1,
    const short* __restrict__ w2p, const float* __restrict__ b2,
    float* __restrict__ gout32, short* __restrict__ gout16) {
    __shared__ __align__(16) char Ab[2][32768];
    int wid = threadIdx.x >> 6, lane = threadIdx.x & 63, lrow = lane & 15, lq = lane >> 4;
    int wm = wid >> 2, wn = wid & 3;
    int va = blockIdx.x >> 3, vb0 = (blockIdx.x & 7) * 4;
    int srow = threadIdx.x >> 2, sseg = threadIdx.x & 3;
    int sb = srow >> 5, sc = srow & 31;
    bfrag zf;
    #pragma unroll
    for (int r = 0; r < 8; ++r) zf[r] = 0;
    float bb1[2], bb2[2];
    #pragma unroll
    for (int ct = 0; ct < 2; ++ct) {
        bb1[ct] = b1[wn * 32 + ct * 16 + lrow];
        bb2[ct] = b2[wn * 32 + ct * 16 + lrow];
    }
    f32x4 zv = {0.f, 0.f, 0.f, 0.f};
    f32x4 acc[4][2];
    #pragma unroll
    for (int rt = 0; rt < 4; ++rt) { acc[rt][0] = zv; acc[rt][1] = zv; }
    const bfrag* bp1 = (const bfrag*)w1p;

    bfrag Bcur[8];
    #pragma unroll
    for (int s = 0; s < 4; ++s)
        #pragma unroll
        for (int ct = 0; ct < 2; ++ct) Bcur[s * 2 + ct] = bp1[(s * 8 + wn * 2 + ct) * 64 + lane];
    {
        int aa = va - 1, bb = vb0 + sb - 1, cc = sc - 1;
        bool ok = ((unsigned)aa < 32u) && ((unsigned)bb < 32u) && ((unsigned)cc < 32u);
        int soff = ok ? ((aa * 32 + bb) * 32 + cc) * 128 : 0;
        const bfrag* src = (const bfrag*)(gin16 + soff);
        #pragma unroll
        for (int j = 0; j < 4; ++j) {
            int seg = sseg + j * 4;
            bfrag v = src[seg];
            *(bfrag*)(Ab[0] + swz(srow, seg * 16)) = ok ? v : zf;
        }
    }
    __syncthreads();

    #pragma unroll 1
    for (int tap = 0; tap < 27; ++tap) {
        bfrag st[4];
        bool okn = false;
        bfrag Bnxt[8];
        if (tap < 26) {
            int tn = tap + 1;
            int da = tn / 9 - 1, db = (tn / 3) % 3 - 1, dc = tn % 3 - 1;
            int aa = va + da, bb = vb0 + sb + db, cc = sc + dc;
            okn = ((unsigned)aa < 32u) && ((unsigned)bb < 32u) && ((unsigned)cc < 32u);
            int soff = okn ? ((aa * 32 + bb) * 32 + cc) * 128 : 0;
            const bfrag* src = (const bfrag*)(gin16 + soff);
            #pragma unroll
            for (int j = 0; j < 4; ++j) st[j] = src[sseg + j * 4];
            #pragma unroll
            for (int s = 0; s < 4; ++s)
                #pragma unroll
                for (int ct = 0; ct < 2; ++ct)
                    Bnxt[s * 2 + ct] = bp1[((tn * 4 + s) * 8 + wn * 2 + ct) * 64 + lane];
        }
        const char* tbc = Ab[tap & 1];
        #pragma unroll
        for (int s = 0; s < 4; ++s) {
            bfrag av[4];
            #pragma unroll
            for (int rt = 0; rt < 4; ++rt) {
                int row = wm * 64 + rt * 16 + lrow;
                av[rt] = *(const bfrag*)(tbc + swz(row, s * 64 + lq * 16));
            }
            #pragma unroll
            for (int ct = 0; ct < 2; ++ct)
                #pragma unroll
                for (int rt = 0; rt < 4; ++rt) acc[rt][ct] = MFMA(av[rt], Bcur[s * 2 + ct], acc[rt][ct]);
        }
        if (tap < 26) {
            char* nb = Ab[(tap + 1) & 1];
            #pragma unroll
            for (int j = 0; j < 4; ++j)
                *(bfrag*)(nb + swz(srow, (sseg + j * 4) * 16)) = okn ? st[j] : zf;
            #pragma unroll
            for (int i = 0; i < 8; ++i) Bcur[i] = Bnxt[i];
        }
        __syncthreads();
    }

    #pragma unroll
    for (int rt = 0; rt < 4; ++rt)
        #pragma unroll
        for (int ct = 0; ct < 2; ++ct)
            #pragma unroll
            for (int r = 0; r < 4; ++r) {
                int row = wm * 64 + rt * 16 + lq * 4 + r, col = wn * 32 + ct * 16 + lrow;
                *(short*)(Ab[0] + swz(row, col * 2)) = f2b(lrelu(acc[rt][ct][r] + bb1[ct]));
            }
    __syncthreads();
    f32x4 acc2[4][2];
    #pragma unroll
    for (int rt = 0; rt < 4; ++rt) { acc2[rt][0] = zv; acc2[rt][1] = zv; }
    const bfrag* bp2 = (const bfrag*)w2p;
    #pragma unroll
    for (int s = 0; s < 4; ++s) {
        bfrag Bv[2];
        #pragma unroll
        for (int ct = 0; ct < 2; ++ct) Bv[ct] = bp2[(s * 8 + wn * 2 + ct) * 64 + lane];
        bfrag av[4];
        #pragma unroll
        for (int rt = 0; rt < 4; ++rt) {
            int row = wm * 64 + rt * 16 + lrow;
            av[rt] = *(const bfrag*)(Ab[0] + swz(row, s * 64 + lq * 16));
        }
        #pragma unroll
        for (int ct = 0; ct < 2; ++ct)
            #pragma unroll
            for (int rt = 0; rt < 4; ++rt) acc2[rt][ct] = MFMA(av[rt], Bv[ct], acc2[rt][ct]);
    }
    #pragma unroll
    for (int rt = 0; rt < 4; ++rt)
        #pragma unroll
        for (int ct = 0; ct < 2; ++ct)
            #pragma unroll
            for (int r = 0; r < 4; ++r) {
                int row = wm * 64 + rt * 16 + lq * 4 + r;
                int voxel = (va * 32 + vb0 + (row >> 5)) * 32 + (row & 31);
                size_t o = (size_t)voxel * 128 + wn * 32 + ct * 16 + lrow;
                float v = lrelu(acc2[rt][ct][r] + bb2[ct] + gin32[o]);
                gout32[o] = v; gout16[o] = f2b(v);
            }
}

// ---------------- head: gather + lin1 + lin2 + linb + sigmoid; block M64, 8 waves ----------------
__global__ __launch_bounds__(512) void k_head(
    const short* __restrict__ g16, const int* __restrict__ vx, const int* __restrict__ vmin,
    const short* __restrict__ w1p, const float* __restrict__ b1,
    const short* __restrict__ w2p, const float* __restrict__ b2,
    const float* __restrict__ W3, const float* __restrict__ b3,
    float* __restrict__ out) {
    __shared__ __align__(16) char tb[16384];
    __shared__ float t2[64][129];
    int wid = threadIdx.x >> 6, lane = threadIdx.x & 63, lrow = lane & 15, lq = lane >> 4;
    int rowbase = blockIdx.x * 64;
    int goff[4];
    #pragma unroll
    for (int rt = 0; rt < 4; ++rt) {
        int m = rowbase + rt * 16 + lrow;
        int v0 = vx[m * 3 + 0] - vmin[0];
        int v1 = vx[m * 3 + 1] - vmin[1];
        int v2 = vx[m * 3 + 2] - vmin[2];
        goff[rt] = ((v0 * 32 + v1) * 32 + v2) * 128;
    }
    float bb1 = b1[wid * 16 + lrow], bb2 = b2[wid * 16 + lrow];
    f32x4 zv = {0.f, 0.f, 0.f, 0.f};
    f32x4 acc[4];
    #pragma unroll
    for (int rt = 0; rt < 4; ++rt) acc[rt] = zv;
    const bfrag* bp1 = (const bfrag*)w1p;
    #pragma unroll
    for (int s = 0; s < 4; ++s) {
        bfrag B = bp1[(s * 8 + wid) * 64 + lane];
        #pragma unroll
        for (int rt = 0; rt < 4; ++rt) {
            bfrag a = *((const bfrag*)(g16 + goff[rt]) + s * 4 + lq);
            acc[rt] = MFMA(a, B, acc[rt]);
        }
    }
    #pragma unroll
    for (int rt = 0; rt < 4; ++rt)
        #pragma unroll
        for (int r = 0; r < 4; ++r) {
            int row = rt * 16 + lq * 4 + r, col = wid * 16 + lrow;
            *(short*)(tb + swz(row, col * 2)) = f2b(lrelu(acc[rt][r] + bb1));
        }
    __syncthreads();
    f32x4 acc2[4];
    #pragma unroll
    for (int rt = 0; rt < 4; ++rt) acc2[rt] = zv;
    const bfrag* bp2 = (const bfrag*)w2p;
    #pragma unroll
    for (int s = 0; s < 4; ++s) {
        bfrag B = bp2[(s * 8 + wid) * 64 + lane];
        #pragma unroll
        for (int rt = 0; rt < 4; ++rt) {
            int row = rt * 16 + lrow;
            bfrag av = *(const bfrag*)(tb + swz(row, s * 64 + lq * 16));
            acc2[rt] = MFMA(av, B, acc2[rt]);
        }
    }
    #pragma unroll
    for (int rt = 0; rt < 4; ++rt)
        #pragma unroll
        for (int r = 0; r < 4; ++r) {
            int row = rt * 16 + lq * 4 + r, col = wid * 16 + lrow;
            t2[row][col] = lrelu(acc2[rt][r] + bb2);
        }
    __syncthreads();
    if (threadIdx.x < 192) {
        int row = threadIdx.x & 63, c = threadIdx.x >> 6;
        float s = b3[c];
        #pragma unroll 4
        for (int k = 0; k < 128; ++k) s += t2[row][k] * W3[k * 3 + c];
        out[(size_t)(rowbase + row) * 3 + c] = 1.f / (1.f + expf(-s));
    }
}

// ---------------- small kernels ----------------
__global__ void k_vmin(const int* __restrict__ vx, int M, int* __restrict__ vmin) {
    __shared__ int sm[3 * 256];
    int t = threadIdx.x;
    int m0 = 0x7fffffff, m1 = 0x7fffffff, m2 = 0x7fffffff;
    for (int i = t; i < M; i += 256) {
        m0 = min(m0, vx[i * 3 + 0]); m1 = min(m1, vx[i * 3 + 1]); m2 = min(m2, vx[i * 3 + 2]);
    }
    sm[t] = m0; sm[256 + t] = m1; sm[512 + t] = m2;
    __syncthreads();
    for (int s = 128; s > 0; s >>= 1) {
        if (t < s) {
            sm[t] = min(sm[t], sm[t + s]);
            sm[256 + t] = min(sm[256 + t], sm[256 + t + s]);
            sm[512 + t] = min(sm[512 + t], sm[512 + t + s]);
        }
        __syncthreads();
    }
    if (t == 0) { vmin[0] = sm[0]; vmin[1] = sm[256]; vmin[2] = sm[512]; }
}

__global__ void k_scatter(const float* __restrict__ vf, const int* __restrict__ vx,
                          const int* __restrict__ vmin, float* __restrict__ g32, short* __restrict__ g16) {
    int m = blockIdx.x, j = threadIdx.x;
    int v0 = vx[m * 3 + 0] - vmin[0];
    int v1 = vx[m * 3 + 1] - vmin[1];
    int v2 = vx[m * 3 + 2] - vmin[2];
    size_t o = (size_t)(((v0 * GDIM) + v1) * GDIM + v2) * EF + j;
    float v = vf[(size_t)m * EF + j];
    g32[o] = v; g16[o] = f2b(v);
}

extern "C" void kernel_launch(void* const* d_in, const int* in_sizes, int n_in,
                              void* d_out, int out_size, void* d_ws, size_t ws_size,
                              hipStream_t stream) {
    const int*   pc_idx  = (const int*)  d_in[0];
    const float* pc_xyz  = (const float*)d_in[1];
    const int*   vox_int = (const int*)  d_in[2];
    const int*   vox_idx = (const int*)  d_in[3];
    const float* vox_xyz = (const float*)d_in[4];
    const float* pcf_W1  = (const float*)d_in[5];
    const float* pcf_b1  = (const float*)d_in[6];
    const float* pcf_W2  = (const float*)d_in[7];
    const float* pcf_b2  = (const float*)d_in[8];
    const float* pcres_W1 = (const float*)d_in[9];
    const float* pcres_b1 = (const float*)d_in[10];
    const float* pcres_W2 = (const float*)d_in[11];
    const float* pcres_b2 = (const float*)d_in[12];
    const float* pcc_W1  = (const float*)d_in[13];
    const float* pcc_b1  = (const float*)d_in[14];
    const float* pcc_W2  = (const float*)d_in[15];
    const float* pcc_b2  = (const float*)d_in[16];
    const float* r3_Wc1  = (const float*)d_in[17];
    const float* r3_bc1  = (const float*)d_in[18];
    const float* r3_Wc2  = (const float*)d_in[19];
    const float* r3_bc2  = (const float*)d_in[20];
    const float* lin1_W  = (const float*)d_in[21];
    const float* lin1_b  = (const float*)d_in[22];
    const float* lin2_W  = (const float*)d_in[23];
    const float* lin2_b  = (const float*)d_in[24];
    const float* linb_W  = (const float*)d_in[25];
    const float* linb_b  = (const float*)d_in[26];

    const size_t NE = (size_t)NPTS * EF;   // 4M elements
    float* A32 = (float*)d_ws;
    float* B32 = A32 + NE;
    short* A16 = (short*)(B32 + NE);
    short* B16 = A16 + NE;
    float* Y32 = (float*)(B16 + NE);
    short* Y16 = (short*)(Y32 + NE);
    short* pcf_w1p = Y16 + NE;                 // 1 step
    short* pcf_w2p = pcf_w1p + 1 * 4096;
    short* pcc_w1p = pcf_w2p + 4 * 4096;       // 6 layers x 5 steps
    short* pcc_w2p = pcc_w1p + 6 * 5 * 4096;   // 6 x 4
    short* pcr_w1p = pcc_w2p + 6 * 4 * 4096;   // 7 x 4
    short* pcr_w2p = pcr_w1p + 7 * 4 * 4096;
    short* wc2p    = pcr_w2p + 7 * 4 * 4096;   // 8 x 4
    short* lin1p   = wc2p    + 8 * 4 * 4096;
    short* lin2p   = lin1p   + 4 * 4096;
    short* wc1p    = lin2p   + 4 * 4096;       // 108 steps (one layer at a time)
    int*   vmin    = (int*)(wc1p + 108 * 4096);

    // ---- pack weights ----
    k_pack_w<<<16, 256, 0, stream>>>(pcf_W1, pcf_w1p, 3, 1, 128, 1);
    k_pack_w<<<64, 256, 0, stream>>>(pcf_W2, pcf_w2p, 128, 4, 128, 1);
    for (int i = 0; i < 6; ++i) {
        k_pack_w<<<80, 256, 0, stream>>>(pcc_W1 + (size_t)i * 131 * 128, pcc_w1p + (size_t)i * 5 * 4096, 131, 5, 128, 1);
        k_pack_w<<<64, 256, 0, stream>>>(pcc_W2 + (size_t)i * 128 * 128, pcc_w2p + (size_t)i * 4 * 4096, 128, 4, 128, 1);
    }
    for (int i = 0; i < 7; ++i) {
        k_pack_w<<<64, 256, 0, stream>>>(pcres_W1 + (size_t)i * 128 * 128, pcr_w1p + (size_t)i * 4 * 4096, 128, 4, 128, 1);
        k_pack_w<<<64, 256, 0, stream>>>(pcres_W2 + (size_t)i * 128 * 128, pcr_w2p + (size_t)i * 4 * 4096, 128, 4, 128, 1);
    }
    for (int i = 0; i < 8; ++i)
        k_pack_w<<<64, 256, 0, stream>>>(r3_Wc2 + (size_t)i * 128 * 128, wc2p + (size_t)i * 4 * 4096, 128, 4, 1, 128);
    k_pack_w<<<64, 256, 0, stream>>>(lin1_W, lin1p, 128, 4, 128, 1);
    k_pack_w<<<64, 256, 0, stream>>>(lin2_W, lin2p, 128, 4, 128, 1);

    // ---- point-cloud stack with fused residual blocks (bf16 activations only) ----
    k_pcfirst<<<NPTS * KNN / 128, 512, 0, stream>>>(pc_xyz, pcf_w1p, pcf_b1, pcf_w2p, pcf_b2,
        pcr_w1p, pcres_b1, pcr_w2p, pcres_b2, nullptr, A16);
    short* cur16 = A16; short* nxt16 = B16;
    for (int i = 0; i < 5; ++i) {
        k_pcconv<<<NPTS * KNN / 128, 512, 0, stream>>>(cur16, pc_idx, pc_xyz,
            pcc_w1p + (size_t)i * 5 * 4096, pcc_b1 + i * EF,
            pcc_w2p + (size_t)i * 4 * 4096, pcc_b2 + i * EF,
            pcr_w1p + (size_t)(i + 1) * 4 * 4096, pcres_b1 + (i + 1) * EF,
            pcr_w2p + (size_t)(i + 1) * 4 * 4096, pcres_b2 + (i + 1) * EF,
            nullptr, nxt16);
        short* t = cur16; cur16 = nxt16; nxt16 = t;
    }
    // voxel layer: writes fp32 too (feeds the dense-grid scatter)
    k_pcconv<<<MVOX * KNN / 128, 512, 0, stream>>>(cur16, vox_idx, vox_xyz,
        pcc_w1p + (size_t)5 * 5 * 4096, pcc_b1 + 5 * EF,
        pcc_w2p + (size_t)5 * 4 * 4096, pcc_b2 + 5 * EF,
        pcr_w1p + (size_t)6 * 4 * 4096, pcres_b1 + 6 * EF,
        pcr_w2p + (size_t)6 * 4 * 4096, pcres_b2 + 6 * EF,
        A32, A16);   // voxfeat: fp32 in A32 rows 0..8191, bf16 in A16

    k_vmin<<<1, 256, 0, stream>>>(vox_int, MVOX, vmin);
    hipMemsetAsync(B32, 0, NE * sizeof(float), stream);
    hipMemsetAsync(B16, 0, NE * sizeof(short), stream);
    k_scatter<<<MVOX, 128, 0, stream>>>(A32, vox_int, vmin, B32, B16);

    // ---- 8 x resnet_block_rec3 (ping-pong B <-> Y) ----
    float* cur32 = B32; short* curg = B16;
    float* nxt32 = Y32; short* nxtg = Y16;
    for (int i = 0; i < 8; ++i) {
        k_pack_wc1<<<1728, 256, 0, stream>>>(r3_Wc1 + (size_t)i * 128 * 128 * 27, wc1p);
        k_conv3<<<256, 512, 0, stream>>>(cur32, curg, wc1p, r3_bc1 + i * EF,
                                         wc2p + (size_t)i * 4 * 4096, r3_bc2 + i * EF,
                                         nxt32, nxtg);
        float* t32 = cur32; cur32 = nxt32; nxt32 = t32;
        short* t16 = curg; curg = nxtg; nxtg = t16;
    }

    // ---- head ----
    k_head<<<MVOX / 64, 512, 0, stream>>>(curg, vox_int, vmin,
                                          lin1p, lin1_b, lin2p, lin2_b, linb_W, linb_b,
                                          (float*)d_out);
}

// Round 8
// 701.923 us; speedup vs baseline: 3.4072x; 1.0656x over previous
//
#include <hip/hip_runtime.h>
#include <math.h>

#define EF 128
#define NPTS 32768
#define KNN 8
#define MVOX 8192
#define GDIM 32
#define NVOXG (GDIM*GDIM*GDIM)

typedef __attribute__((ext_vector_type(8))) short bfrag;   // 8 x bf16
typedef __attribute__((ext_vector_type(4))) float f32x4;

__device__ __forceinline__ float lrelu(float x) { return x > 0.f ? x : 0.01f * x; }
__device__ __forceinline__ short f2b(float f) {            // fp32 -> bf16 (RNE)
    unsigned u = __float_as_uint(f);
    return (short)((u + 0x7fff + ((u >> 16) & 1)) >> 16);
}
#define MFMA(a,b,c) __builtin_amdgcn_mfma_f32_16x16x32_bf16((a),(b),(c),0,0,0)
// LDS tile addressing: row-major 256B rows, XOR swizzle on byte bits 4-6
__device__ __forceinline__ int swz(int row, int bytecol) {
    return row * 256 + (bytecol ^ ((row & 7) << 4));
}

// ---------------- weight packing: W[k][col] (strided) -> [step][ct][lane][8] bf16 ----------------
__global__ void k_pack_w(const float* __restrict__ src, short* __restrict__ dst,
                         int K_real, int n_steps, int k_str, int c_str) {
    int t = blockIdx.x * 256 + threadIdx.x;
    int total = n_steps * 4096;
    if (t >= total) return;
    int r = t & 7, l = (t >> 3) & 63, ct = (t >> 9) & 7, s = t >> 12;
    int k = s * 32 + (l >> 4) * 8 + r;
    int col = ct * 16 + (l & 15);
    float v = (k < K_real) ? src[(size_t)k * k_str + (size_t)col * c_str] : 0.f;
    dst[t] = f2b(v);
}
// conv3x3x3 weights [o][ci][27] -> [tap*4+cc][ct][lane][8]
__global__ void k_pack_wc1(const float* __restrict__ src, short* __restrict__ dst) {
    int t = blockIdx.x * 256 + threadIdx.x;
    if (t >= 108 * 4096) return;
    int r = t & 7, l = (t >> 3) & 63, ct = (t >> 9) & 7, s = t >> 12;
    int tap = s >> 2;
    int ci = (s & 3) * 32 + (l >> 4) * 8 + r;
    int col = ct * 16 + (l & 15);
    dst[t] = f2b(src[((size_t)col * 128 + ci) * 27 + tap]);
}

// ============ template: block = 128 gather-rows (16 out rows), 8 waves 2Mx4N, fused res ============

// ---------------- pc_conv_first: MFMA phase-1 + GEMM2 + pool + fused res0 ----------------
__global__ __launch_bounds__(512) void k_pcfirst(
    const float* __restrict__ xyz, const short* __restrict__ w1p, const float* __restrict__ b1,
    const short* __restrict__ w2p, const float* __restrict__ b2,
    const short* __restrict__ rw1p, const float* __restrict__ rb1,
    const short* __restrict__ rw2p, const float* __restrict__ rb2,
    float* __restrict__ out32, short* __restrict__ out16) {
    __shared__ __align__(16) char tb[32768];
    int wid = threadIdx.x >> 6, lane = threadIdx.x & 63, lrow = lane & 15, lq = lane >> 4;
    int wm = wid >> 2, wn = wid & 3;
    int rowbase = blockIdx.x * 128;
    f32x4 zv = {0.f, 0.f, 0.f, 0.f};
    // ---- phase 1: 3->128 via 1-k-step MFMA ----
    {
        f32x4 acc1[4][2];
        #pragma unroll
        for (int rt = 0; rt < 4; ++rt) { acc1[rt][0] = zv; acc1[rt][1] = zv; }
        bfrag Bv[2];
        #pragma unroll
        for (int ct = 0; ct < 2; ++ct) Bv[ct] = ((const bfrag*)w1p)[(wn * 2 + ct) * 64 + lane];
        #pragma unroll
        for (int rt = 0; rt < 4; ++rt) {
            bfrag a4;
            #pragma unroll
            for (int r = 0; r < 8; ++r) a4[r] = 0;
            if (lq == 0) {
                int gr = rowbase + wm * 64 + rt * 16 + lrow;
                a4[0] = f2b(xyz[gr * 3]); a4[1] = f2b(xyz[gr * 3 + 1]); a4[2] = f2b(xyz[gr * 3 + 2]);
            }
            #pragma unroll
            for (int ct = 0; ct < 2; ++ct) acc1[rt][ct] = MFMA(a4, Bv[ct], acc1[rt][ct]);
        }
        float bb1[2];
        #pragma unroll
        for (int ct = 0; ct < 2; ++ct) bb1[ct] = b1[wn * 32 + ct * 16 + lrow];
        #pragma unroll
        for (int rt = 0; rt < 4; ++rt)
            #pragma unroll
            for (int ct = 0; ct < 2; ++ct)
                #pragma unroll
                for (int r = 0; r < 4; ++r) {
                    int row = wm * 64 + rt * 16 + lq * 4 + r, col = wn * 32 + ct * 16 + lrow;
                    *(short*)(tb + swz(row, col * 2)) = f2b(lrelu(acc1[rt][ct][r] + bb1[ct]));
                }
    }
    __syncthreads();
    // ---- GEMM2 + pool ----
    float bb2[2];
    #pragma unroll
    for (int ct = 0; ct < 2; ++ct) bb2[ct] = b2[wn * 32 + ct * 16 + lrow];
    f32x4 acc[4][2];
    #pragma unroll
    for (int rt = 0; rt < 4; ++rt) { acc[rt][0] = zv; acc[rt][1] = zv; }
    const bfrag* bp2 = (const bfrag*)w2p;
    #pragma unroll
    for (int s = 0; s < 4; ++s) {
        bfrag Bv[2];
        #pragma unroll
        for (int ct = 0; ct < 2; ++ct) Bv[ct] = bp2[(s * 8 + wn * 2 + ct) * 64 + lane];
        bfrag av[4];
        #pragma unroll
        for (int rt = 0; rt < 4; ++rt) {
            int row = wm * 64 + rt * 16 + lrow;
            av[rt] = *(const bfrag*)(tb + swz(row, s * 64 + lq * 16));
        }
        #pragma unroll
        for (int ct = 0; ct < 2; ++ct)
            #pragma unroll
            for (int rt = 0; rt < 4; ++rt) acc[rt][ct] = MFMA(av[rt], Bv[ct], acc[rt][ct]);
    }
    float pv[4][2];
    #pragma unroll
    for (int rt = 0; rt < 4; ++rt)
        #pragma unroll
        for (int ct = 0; ct < 2; ++ct) {
            float m = -INFINITY;
            #pragma unroll
            for (int r = 0; r < 4; ++r) m = fmaxf(m, acc[rt][ct][r] + bb2[ct]);
            m = fmaxf(m, __shfl_xor(m, 16, 64));
            pv[rt][ct] = lrelu(m);
        }
    // ---- pooled x -> LDS tiles ----
    __syncthreads();
    float* xf = (float*)(tb + 4096);            // [16][130]
    char*  tres = tb + 12544;                   // 16-row swizzled bf16 tile
    if ((lq & 1) == 0) {
        #pragma unroll
        for (int rt = 0; rt < 4; ++rt)
            #pragma unroll
            for (int ct = 0; ct < 2; ++ct) {
                int row = wm * 8 + rt * 2 + (lq >> 1), col = wn * 32 + ct * 16 + lrow;
                *(short*)(tb + swz(row, col * 2)) = f2b(pv[rt][ct]);
                xf[row * 130 + col] = pv[rt][ct];
            }
    }
    __syncthreads();
    // ---- fused res: GEMM1 ----
    {
        f32x4 r1 = zv;
        #pragma unroll
        for (int s = 0; s < 4; ++s) {
            bfrag B = ((const bfrag*)rw1p)[(s * 8 + wid) * 64 + lane];
            bfrag a = *(const bfrag*)(tb + swz(lrow, s * 64 + lq * 16));
            r1 = MFMA(a, B, r1);
        }
        float rb1v = rb1[wid * 16 + lrow];
        #pragma unroll
        for (int r = 0; r < 4; ++r) {
            int row = lq * 4 + r;
            *(short*)(tres + swz(row, (wid * 16 + lrow) * 2)) = f2b(lrelu(r1[r] + rb1v));
        }
    }
    __syncthreads();
    {
        f32x4 r2 = zv;
        #pragma unroll
        for (int s = 0; s < 4; ++s) {
            bfrag B = ((const bfrag*)rw2p)[(s * 8 + wid) * 64 + lane];
            bfrag a = *(const bfrag*)(tres + swz(lrow, s * 64 + lq * 16));
            r2 = MFMA(a, B, r2);
        }
        float rb2v = rb2[wid * 16 + lrow];
        int p0 = blockIdx.x * 16;
        #pragma unroll
        for (int r = 0; r < 4; ++r) {
            int row = lq * 4 + r, col = wid * 16 + lrow;
            float v = lrelu(r2[r] + rb2v + xf[row * 130 + col]);
            size_t o = (size_t)(p0 + row) * 128 + col;
            out16[o] = f2b(v);
            if (out32) out32[o] = v;
        }
    }
}

// ---------------- pc_conv: staged gather + 131->128 + 128->128 + pool + fused res ----------------
__global__ __launch_bounds__(512) void k_pcconv(
    const short* __restrict__ fin16, const int* __restrict__ idx, const float* __restrict__ xyz,
    const short* __restrict__ w1p, const float* __restrict__ b1,
    const short* __restrict__ w2p, const float* __restrict__ b2,
    const short* __restrict__ rw1p, const float* __restrict__ rb1,
    const short* __restrict__ rw2p, const float* __restrict__ rb2,
    float* __restrict__ out32, short* __restrict__ out16) {
    __shared__ __align__(16) char tb[32768];
    int wid = threadIdx.x >> 6, lane = threadIdx.x & 63, lrow = lane & 15, lq = lane >> 4;
    int wm = wid >> 2, wn = wid & 3;
    int rowbase = blockIdx.x * 128;
    f32x4 zv = {0.f, 0.f, 0.f, 0.f};
    // stage gathered rows once per block
    {
        int srow = threadIdx.x >> 2, sseg = threadIdx.x & 3;
        int nb = idx[rowbase + srow];
        const bfrag* src = (const bfrag*)(fin16 + (size_t)nb * 128);
        #pragma unroll
        for (int j = 0; j < 4; ++j) {
            int seg = sseg + j * 4;
            bfrag v = src[seg];
            *(bfrag*)(tb + swz(srow, seg * 16)) = v;
        }
    }
    __syncthreads();
    float bb1[2], bb2[2];
    #pragma unroll
    for (int ct = 0; ct < 2; ++ct) {
        bb1[ct] = b1[wn * 32 + ct * 16 + lrow];
        bb2[ct] = b2[wn * 32 + ct * 16 + lrow];
    }
    f32x4 acc[4][2];
    #pragma unroll
    for (int rt = 0; rt < 4; ++rt) { acc[rt][0] = zv; acc[rt][1] = zv; }
    const bfrag* bp1 = (const bfrag*)w1p;
    #pragma unroll
    for (int s = 0; s < 4; ++s) {
        bfrag Bv[2];
        #pragma unroll
        for (int ct = 0; ct < 2; ++ct) Bv[ct] = bp1[(s * 8 + wn * 2 + ct) * 64 + lane];
        bfrag av[4];
        #pragma unroll
        for (int rt = 0; rt < 4; ++rt) {
            int row = wm * 64 + rt * 16 + lrow;
            av[rt] = *(const bfrag*)(tb + swz(row, s * 64 + lq * 16));
        }
        #pragma unroll
        for (int ct = 0; ct < 2; ++ct)
            #pragma unroll
            for (int rt = 0; rt < 4; ++rt) acc[rt][ct] = MFMA(av[rt], Bv[ct], acc[rt][ct]);
    }
    {   // k-step 4: xyz concat (cols 128..130)
        bfrag Bv[2];
        #pragma unroll
        for (int ct = 0; ct < 2; ++ct) Bv[ct] = bp1[(32 + wn * 2 + ct) * 64 + lane];
        #pragma unroll
        for (int rt = 0; rt < 4; ++rt) {
            bfrag a4;
            #pragma unroll
            for (int r = 0; r < 8; ++r) a4[r] = 0;
            if (lq == 0) {
                int gr = rowbase + wm * 64 + rt * 16 + lrow;
                a4[0] = f2b(xyz[gr * 3]); a4[1] = f2b(xyz[gr * 3 + 1]); a4[2] = f2b(xyz[gr * 3 + 2]);
            }
            #pragma unroll
            for (int ct = 0; ct < 2; ++ct) acc[rt][ct] = MFMA(a4, Bv[ct], acc[rt][ct]);
        }
    }
    __syncthreads();   // all GEMM1 reads of tb done before overwrite
    #pragma unroll
    for (int rt = 0; rt < 4; ++rt)
        #pragma unroll
        for (int ct = 0; ct < 2; ++ct)
            #pragma unroll
            for (int r = 0; r < 4; ++r) {
                int row = wm * 64 + rt * 16 + lq * 4 + r, col = wn * 32 + ct * 16 + lrow;
                *(short*)(tb + swz(row, col * 2)) = f2b(lrelu(acc[rt][ct][r] + bb1[ct]));
            }
    __syncthreads();
    f32x4 acc2[4][2];
    #pragma unroll
    for (int rt = 0; rt < 4; ++rt) { acc2[rt][0] = zv; acc2[rt][1] = zv; }
    const bfrag* bp2 = (const bfrag*)w2p;
    #pragma unroll
    for (int s = 0; s < 4; ++s) {
        bfrag Bv[2];
        #pragma unroll
        for (int ct = 0; ct < 2; ++ct) Bv[ct] = bp2[(s * 8 + wn * 2 + ct) * 64 + lane];
        bfrag av[4];
        #pragma unroll
        for (int rt = 0; rt < 4; ++rt) {
            int row = wm * 64 + rt * 16 + lrow;
            av[rt] = *(const bfrag*)(tb + swz(row, s * 64 + lq * 16));
        }
        #pragma unroll
        for (int ct = 0; ct < 2; ++ct)
            #pragma unroll
            for (int rt = 0; rt < 4; ++rt) acc2[rt][ct] = MFMA(av[rt], Bv[ct], acc2[rt][ct]);
    }
    float pv[4][2];
    #pragma unroll
    for (int rt = 0; rt < 4; ++rt)
        #pragma unroll
        for (int ct = 0; ct < 2; ++ct) {
            float m = -INFINITY;
            #pragma unroll
            for (int r = 0; r < 4; ++r) m = fmaxf(m, acc2[rt][ct][r] + bb2[ct]);
            m = fmaxf(m, __shfl_xor(m, 16, 64));
            pv[rt][ct] = lrelu(m);
        }
    // ---- pooled x -> LDS tiles ----
    __syncthreads();
    float* xf = (float*)(tb + 4096);            // [16][130]
    char*  tres = tb + 12544;
    if ((lq & 1) == 0) {
        #pragma unroll
        for (int rt = 0; rt < 4; ++rt)
            #pragma unroll
            for (int ct = 0; ct < 2; ++ct) {
                int row = wm * 8 + rt * 2 + (lq >> 1), col = wn * 32 + ct * 16 + lrow;
                *(short*)(tb + swz(row, col * 2)) = f2b(pv[rt][ct]);
                xf[row * 130 + col] = pv[rt][ct];
            }
    }
    __syncthreads();
    // ---- fused res ----
    {
        f32x4 r1 = zv;
        #pragma unroll
        for (int s = 0; s < 4; ++s) {
            bfrag B = ((const bfrag*)rw1p)[(s * 8 + wid) * 64 + lane];
            bfrag a = *(const bfrag*)(tb + swz(lrow, s * 64 + lq * 16));
            r1 = MFMA(a, B, r1);
        }
        float rb1v = rb1[wid * 16 + lrow];
        #pragma unroll
        for (int r = 0; r < 4; ++r) {
            int row = lq * 4 + r;
            *(short*)(tres + swz(row, (wid * 16 + lrow) * 2)) = f2b(lrelu(r1[r] + rb1v));
        }
    }
    __syncthreads();
    {
        f32x4 r2 = zv;
        #pragma unroll
        for (int s = 0; s < 4; ++s) {
            bfrag B = ((const bfrag*)rw2p)[(s * 8 + wid) * 64 + lane];
            bfrag a = *(const bfrag*)(tres + swz(lrow, s * 64 + lq * 16));
            r2 = MFMA(a, B, r2);
        }
        float rb2v = rb2[wid * 16 + lrow];
        int p0 = blockIdx.x * 16;
        #pragma unroll
        for (int r = 0; r < 4; ++r) {
            int row = lq * 4 + r, col = wid * 16 + lrow;
            float v = lrelu(r2[r] + rb2v + xf[row * 130 + col]);
            size_t o = (size_t)(p0 + row) * 128 + col;
            out16[o] = f2b(v);
            if (out32) out32[o] = v;
        }
    }
}

// ---------------- conv3d 3x3x3: per-da slab staging (dbuf), 9 barrier-free taps/slab ----------------
// block = 2 output b-lines (M64), grid 512; 8 waves 2Mx4N (wave M32xN32)
__global__ __launch_bounds__(512) void k_conv3(
    const float* __restrict__ gin32, const short* __restrict__ gin16,
    const short* __restrict__ w1p, const float* __restrict__ b1,
    const short* __restrict__ w2p, const float* __restrict__ b2,
    float* __restrict__ gout32, short* __restrict__ gout16) {
    __shared__ __align__(16) char Ab[2][32768];
    int wid = threadIdx.x >> 6, lane = threadIdx.x & 63, lrow = lane & 15, lq = lane >> 4;
    int wm = wid >> 2, wn = wid & 3;
    int va = blockIdx.x >> 4, vb0 = (blockIdx.x & 15) * 2;
    int srow = threadIdx.x >> 2, sseg = threadIdx.x & 3;
    int sbl = srow >> 5, sc = srow & 31;   // slab row -> (input b-line 0..3, c)
    bfrag zf;
    #pragma unroll
    for (int r = 0; r < 8; ++r) zf[r] = 0;
    f32x4 zv = {0.f, 0.f, 0.f, 0.f};
    f32x4 acc[2][2];
    #pragma unroll
    for (int rt = 0; rt < 2; ++rt) { acc[rt][0] = zv; acc[rt][1] = zv; }
    const bfrag* bp1 = (const bfrag*)w1p;

    int sb = vb0 - 1 + sbl;                 // input b for this staging row
    bool okb = (unsigned)sb < 32u;
    // prologue: stage slab for da=-1 into Ab[0]
    {
        int aa = va - 1;
        bool ok = okb && ((unsigned)aa < 32u);
        size_t soff = ok ? (size_t)((aa * 32 + sb) * 32 + sc) * 128 : 0;
        const bfrag* src = (const bfrag*)(gin16 + soff);
        #pragma unroll
        for (int j = 0; j < 4; ++j) {
            int seg = sseg + j * 4;
            bfrag v = src[seg];
            *(bfrag*)(Ab[0] + swz(srow, seg * 16)) = ok ? v : zf;
        }
    }
    __syncthreads();

    #pragma unroll 1
    for (int dai = 0; dai < 3; ++dai) {
        // issue next-slab loads early (hide under this slab's 144 MFMAs)
        bfrag st[4];
        bool okn = false;
        if (dai < 2) {
            int aa = va + dai;              // next da = dai
            okn = okb && ((unsigned)aa < 32u);
            size_t soff = okn ? (size_t)((aa * 32 + sb) * 32 + sc) * 128 : 0;
            const bfrag* src = (const bfrag*)(gin16 + soff);
            #pragma unroll
            for (int j = 0; j < 4; ++j) st[j] = src[sseg + j * 4];
        }
        const char* slab = Ab[dai & 1];
        int tapbase = dai * 9;
        // 9 taps, no barriers
        #pragma unroll 3
        for (int t9 = 0; t9 < 9; ++t9) {
            int db = t9 / 3 - 1, dc = t9 % 3 - 1;
            int tap = tapbase + t9;
            int blr = (wm + db + 1) * 32;   // slab row base for this wave's output b-line
            #pragma unroll
            for (int s = 0; s < 4; ++s) {
                bfrag Bv[2];
                #pragma unroll
                for (int ct = 0; ct < 2; ++ct)
                    Bv[ct] = bp1[((tap * 4 + s) * 8 + wn * 2 + ct) * 64 + lane];
                bfrag av[2];
                #pragma unroll
                for (int rt = 0; rt < 2; ++rt) {
                    int ci = rt * 16 + lrow + dc;
                    bool ok = (unsigned)ci < 32u;
                    int sl = blr + (ok ? ci : 0);
                    bfrag t = *(const bfrag*)(slab + swz(sl, s * 64 + lq * 16));
                    av[rt] = ok ? t : zf;
                }
                #pragma unroll
                for (int ct = 0; ct < 2; ++ct)
                    #pragma unroll
                    for (int rt = 0; rt < 2; ++rt) acc[rt][ct] = MFMA(av[rt], Bv[ct], acc[rt][ct]);
            }
        }
        // write next slab into the other buffer
        if (dai < 2) {
            char* nb = Ab[(dai + 1) & 1];
            #pragma unroll
            for (int j = 0; j < 4; ++j)
                *(bfrag*)(nb + swz(srow, (sseg + j * 4) * 16)) = okn ? st[j] : zf;
        }
        __syncthreads();
    }

    // epilogue: bias+lrelu -> t tile (reuse Ab[0]); fused 1x1 + residual
    float bb1[2], bb2[2];
    #pragma unroll
    for (int ct = 0; ct < 2; ++ct) {
        bb1[ct] = b1[wn * 32 + ct * 16 + lrow];
        bb2[ct] = b2[wn * 32 + ct * 16 + lrow];
    }
    #pragma unroll
    for (int rt = 0; rt < 2; ++rt)
        #pragma unroll
        for (int ct = 0; ct < 2; ++ct)
            #pragma unroll
            for (int r = 0; r < 4; ++r) {
                int row = wm * 32 + rt * 16 + lq * 4 + r, col = wn * 32 + ct * 16 + lrow;
                *(short*)(Ab[0] + swz(row, col * 2)) = f2b(lrelu(acc[rt][ct][r] + bb1[ct]));
            }
    __syncthreads();
    f32x4 acc2[2][2];
    #pragma unroll
    for (int rt = 0; rt < 2; ++rt) { acc2[rt][0] = zv; acc2[rt][1] = zv; }
    const bfrag* bp2 = (const bfrag*)w2p;
    #pragma unroll
    for (int s = 0; s < 4; ++s) {
        bfrag Bv[2];
        #pragma unroll
        for (int ct = 0; ct < 2; ++ct) Bv[ct] = bp2[(s * 8 + wn * 2 + ct) * 64 + lane];
        bfrag av[2];
        #pragma unroll
        for (int rt = 0; rt < 2; ++rt) {
            int row = wm * 32 + rt * 16 + lrow;
            av[rt] = *(const bfrag*)(Ab[0] + swz(row, s * 64 + lq * 16));
        }
        #pragma unroll
        for (int ct = 0; ct < 2; ++ct)
            #pragma unroll
            for (int rt = 0; rt < 2; ++rt) acc2[rt][ct] = MFMA(av[rt], Bv[ct], acc2[rt][ct]);
    }
    #pragma unroll
    for (int rt = 0; rt < 2; ++rt)
        #pragma unroll
        for (int ct = 0; ct < 2; ++ct)
            #pragma unroll
            for (int r = 0; r < 4; ++r) {
                int row = wm * 32 + rt * 16 + lq * 4 + r;   // row<32 within wave b-line
                int voxel = (va * 32 + vb0 + wm) * 32 + row - wm * 32 + wm * 32;  // = (va*32+vb0+wm)*32 + (rt*16+lq*4+r)
                int c = rt * 16 + lq * 4 + r;
                voxel = (va * 32 + vb0 + wm) * 32 + c;
                size_t o = (size_t)voxel * 128 + wn * 32 + ct * 16 + lrow;
                float v = lrelu(acc2[rt][ct][r] + bb2[ct] + gin32[o]);
                gout32[o] = v; gout16[o] = f2b(v);
            }
}

// ---------------- head: gather + lin1 + lin2 + linb + sigmoid; block M64, 8 waves ----------------
__global__ __launch_bounds__(512) void k_head(
    const short* __restrict__ g16, const int* __restrict__ vx, const int* __restrict__ vmin,
    const short* __restrict__ w1p, const float* __restrict__ b1,
    const short* __restrict__ w2p, const float* __restrict__ b2,
    const float* __restrict__ W3, const float* __restrict__ b3,
    float* __restrict__ out) {
    __shared__ __align__(16) char tb[16384];
    __shared__ float t2[64][129];
    int wid = threadIdx.x >> 6, lane = threadIdx.x & 63, lrow = lane & 15, lq = lane >> 4;
    int rowbase = blockIdx.x * 64;
    int goff[4];
    #pragma unroll
    for (int rt = 0; rt < 4; ++rt) {
        int m = rowbase + rt * 16 + lrow;
        int v0 = vx[m * 3 + 0] - vmin[0];
        int v1 = vx[m * 3 + 1] - vmin[1];
        int v2 = vx[m * 3 + 2] - vmin[2];
        goff[rt] = ((v0 * 32 + v1) * 32 + v2) * 128;
    }
    float bb1 = b1[wid * 16 + lrow], bb2 = b2[wid * 16 + lrow];
    f32x4 zv = {0.f, 0.f, 0.f, 0.f};
    f32x4 acc[4];
    #pragma unroll
    for (int rt = 0; rt < 4; ++rt) acc[rt] = zv;
    const bfrag* bp1 = (const bfrag*)w1p;
    #pragma unroll
    for (int s = 0; s < 4; ++s) {
        bfrag B = bp1[(s * 8 + wid) * 64 + lane];
        #pragma unroll
        for (int rt = 0; rt < 4; ++rt) {
            bfrag a = *((const bfrag*)(g16 + goff[rt]) + s * 4 + lq);
            acc[rt] = MFMA(a, B, acc[rt]);
        }
    }
    #pragma unroll
    for (int rt = 0; rt < 4; ++rt)
        #pragma unroll
        for (int r = 0; r < 4; ++r) {
            int row = rt * 16 + lq * 4 + r, col = wid * 16 + lrow;
            *(short*)(tb + swz(row, col * 2)) = f2b(lrelu(acc[rt][r] + bb1));
        }
    __syncthreads();
    f32x4 acc2[4];
    #pragma unroll
    for (int rt = 0; rt < 4; ++rt) acc2[rt] = zv;
    const bfrag* bp2 = (const bfrag*)w2p;
    #pragma unroll
    for (int s = 0; s < 4; ++s) {
        bfrag B = bp2[(s * 8 + wid) * 64 + lane];
        #pragma unroll
        for (int rt = 0; rt < 4; ++rt) {
            int row = rt * 16 + lrow;
            bfrag av = *(const bfrag*)(tb + swz(row, s * 64 + lq * 16));
            acc2[rt] = MFMA(av, B, acc2[rt]);
        }
    }
    #pragma unroll
    for (int rt = 0; rt < 4; ++rt)
        #pragma unroll
        for (int r = 0; r < 4; ++r) {
            int row = rt * 16 + lq * 4 + r, col = wid * 16 + lrow;
            t2[row][col] = lrelu(acc2[rt][r] + bb2);
        }
    __syncthreads();
    if (threadIdx.x < 192) {
        int row = threadIdx.x & 63, c = threadIdx.x >> 6;
        float s = b3[c];
        #pragma unroll 4
        for (int k = 0; k < 128; ++k) s += t2[row][k] * W3[k * 3 + c];
        out[(size_t)(rowbase + row) * 3 + c] = 1.f / (1.f + expf(-s));
    }
}

// ---------------- small kernels ----------------
__global__ void k_vmin(const int* __restrict__ vx, int M, int* __restrict__ vmin) {
    __shared__ int sm[3 * 256];
    int t = threadIdx.x;
    int m0 = 0x7fffffff, m1 = 0x7fffffff, m2 = 0x7fffffff;
    for (int i = t; i < M; i += 256) {
        m0 = min(m0, vx[i * 3 + 0]); m1 = min(m1, vx[i * 3 + 1]); m2 = min(m2, vx[i * 3 + 2]);
    }
    sm[t] = m0; sm[256 + t] = m1; sm[512 + t] = m2;
    __syncthreads();
    for (int s = 128; s > 0; s >>= 1) {
        if (t < s) {
            sm[t] = min(sm[t], sm[t + s]);
            sm[256 + t] = min(sm[256 + t], sm[256 + t + s]);
            sm[512 + t] = min(sm[512 + t], sm[512 + t + s]);
        }
        __syncthreads();
    }
    if (t == 0) { vmin[0] = sm[0]; vmin[1] = sm[256]; vmin[2] = sm[512]; }
}

__global__ void k_scatter(const float* __restrict__ vf, const int* __restrict__ vx,
                          const int* __restrict__ vmin, float* __restrict__ g32, short* __restrict__ g16) {
    int m = blockIdx.x, j = threadIdx.x;
    int v0 = vx[m * 3 + 0] - vmin[0];
    int v1 = vx[m * 3 + 1] - vmin[1];
    int v2 = vx[m * 3 + 2] - vmin[2];
    size_t o = (size_t)(((v0 * GDIM) + v1) * GDIM + v2) * EF + j;
    float v = vf[(size_t)m * EF + j];
    g32[o] = v; g16[o] = f2b(v);
}

extern "C" void kernel_launch(void* const* d_in, const int* in_sizes, int n_in,
                              void* d_out, int out_size, void* d_ws, size_t ws_size,
                              hipStream_t stream) {
    const int*   pc_idx  = (const int*)  d_in[0];
    const float* pc_xyz  = (const float*)d_in[1];
    const int*   vox_int = (const int*)  d_in[2];
    const int*   vox_idx = (const int*)  d_in[3];
    const float* vox_xyz = (const float*)d_in[4];
    const float* pcf_W1  = (const float*)d_in[5];
    const float* pcf_b1  = (const float*)d_in[6];
    const float* pcf_W2  = (const float*)d_in[7];
    const float* pcf_b2  = (const float*)d_in[8];
    const float* pcres_W1 = (const float*)d_in[9];
    const float* pcres_b1 = (const float*)d_in[10];
    const float* pcres_W2 = (const float*)d_in[11];
    const float* pcres_b2 = (const float*)d_in[12];
    const float* pcc_W1  = (const float*)d_in[13];
    const float* pcc_b1  = (const float*)d_in[14];
    const float* pcc_W2  = (const float*)d_in[15];
    const float* pcc_b2  = (const float*)d_in[16];
    const float* r3_Wc1  = (const float*)d_in[17];
    const float* r3_bc1  = (const float*)d_in[18];
    const float* r3_Wc2  = (const float*)d_in[19];
    const float* r3_bc2  = (const float*)d_in[20];
    const float* lin1_W  = (const float*)d_in[21];
    const float* lin1_b  = (const float*)d_in[22];
    const float* lin2_W  = (const float*)d_in[23];
    const float* lin2_b  = (const float*)d_in[24];
    const float* linb_W  = (const float*)d_in[25];
    const float* linb_b  = (const float*)d_in[26];

    const size_t NE = (size_t)NPTS * EF;   // 4M elements
    float* A32 = (float*)d_ws;
    float* B32 = A32 + NE;
    short* A16 = (short*)(B32 + NE);
    short* B16 = A16 + NE;
    float* Y32 = (float*)(B16 + NE);
    short* Y16 = (short*)(Y32 + NE);
    short* pcf_w1p = Y16 + NE;                 // 1 step
    short* pcf_w2p = pcf_w1p + 1 * 4096;
    short* pcc_w1p = pcf_w2p + 4 * 4096;       // 6 layers x 5 steps
    short* pcc_w2p = pcc_w1p + 6 * 5 * 4096;   // 6 x 4
    short* pcr_w1p = pcc_w2p + 6 * 4 * 4096;   // 7 x 4
    short* pcr_w2p = pcr_w1p + 7 * 4 * 4096;
    short* wc2p    = pcr_w2p + 7 * 4 * 4096;   // 8 x 4
    short* lin1p   = wc2p    + 8 * 4 * 4096;
    short* lin2p   = lin1p   + 4 * 4096;
    short* wc1p    = lin2p   + 4 * 4096;       // 108 steps (one layer at a time)
    int*   vmin    = (int*)(wc1p + 108 * 4096);

    // ---- pack weights ----
    k_pack_w<<<16, 256, 0, stream>>>(pcf_W1, pcf_w1p, 3, 1, 128, 1);
    k_pack_w<<<64, 256, 0, stream>>>(pcf_W2, pcf_w2p, 128, 4, 128, 1);
    for (int i = 0; i < 6; ++i) {
        k_pack_w<<<80, 256, 0, stream>>>(pcc_W1 + (size_t)i * 131 * 128, pcc_w1p + (size_t)i * 5 * 4096, 131, 5, 128, 1);
        k_pack_w<<<64, 256, 0, stream>>>(pcc_W2 + (size_t)i * 128 * 128, pcc_w2p + (size_t)i * 4 * 4096, 128, 4, 128, 1);
    }
    for (int i = 0; i < 7; ++i) {
        k_pack_w<<<64, 256, 0, stream>>>(pcres_W1 + (size_t)i * 128 * 128, pcr_w1p + (size_t)i * 4 * 4096, 128, 4, 128, 1);
        k_pack_w<<<64, 256, 0, stream>>>(pcres_W2 + (size_t)i * 128 * 128, pcr_w2p + (size_t)i * 4 * 4096, 128, 4, 128, 1);
    }
    for (int i = 0; i < 8; ++i)
        k_pack_w<<<64, 256, 0, stream>>>(r3_Wc2 + (size_t)i * 128 * 128, wc2p + (size_t)i * 4 * 4096, 128, 4, 1, 128);
    k_pack_w<<<64, 256, 0, stream>>>(lin1_W, lin1p, 128, 4, 128, 1);
    k_pack_w<<<64, 256, 0, stream>>>(lin2_W, lin2p, 128, 4, 128, 1);

    // ---- point-cloud stack with fused residual blocks (bf16 activations only) ----
    k_pcfirst<<<NPTS * KNN / 128, 512, 0, stream>>>(pc_xyz, pcf_w1p, pcf_b1, pcf_w2p, pcf_b2,
        pcr_w1p, pcres_b1, pcr_w2p, pcres_b2, nullptr, A16);
    short* cur16 = A16; short* nxt16 = B16;
    for (int i = 0; i < 5; ++i) {
        k_pcconv<<<NPTS * KNN / 128, 512, 0, stream>>>(cur16, pc_idx, pc_xyz,
            pcc_w1p + (size_t)i * 5 * 4096, pcc_b1 + i * EF,
            pcc_w2p + (size_t)i * 4 * 4096, pcc_b2 + i * EF,
            pcr_w1p + (size_t)(i + 1) * 4 * 4096, pcres_b1 + (i + 1) * EF,
            pcr_w2p + (size_t)(i + 1) * 4 * 4096, pcres_b2 + (i + 1) * EF,
            nullptr, nxt16);
        short* t = cur16; cur16 = nxt16; nxt16 = t;
    }
    // voxel layer: writes fp32 too (feeds the dense-grid scatter)
    k_pcconv<<<MVOX * KNN / 128, 512, 0, stream>>>(cur16, vox_idx, vox_xyz,
        pcc_w1p + (size_t)5 * 5 * 4096, pcc_b1 + 5 * EF,
        pcc_w2p + (size_t)5 * 4 * 4096, pcc_b2 + 5 * EF,
        pcr_w1p + (size_t)6 * 4 * 4096, pcres_b1 + 6 * EF,
        pcr_w2p + (size_t)6 * 4 * 4096, pcres_b2 + 6 * EF,
        A32, A16);   // voxfeat: fp32 in A32 rows 0..8191, bf16 in A16

    k_vmin<<<1, 256, 0, stream>>>(vox_int, MVOX, vmin);
    hipMemsetAsync(B32, 0, NE * sizeof(float), stream);
    hipMemsetAsync(B16, 0, NE * sizeof(short), stream);
    k_scatter<<<MVOX, 128, 0, stream>>>(A32, vox_int, vmin, B32, B16);

    // ---- 8 x resnet_block_rec3 (ping-pong B <-> Y) ----
    float* cur32 = B32; short* curg = B16;
    float* nxt32 = Y32; short* nxtg = Y16;
    for (int i = 0; i < 8; ++i) {
        k_pack_wc1<<<1728, 256, 0, stream>>>(r3_Wc1 + (size_t)i * 128 * 128 * 27, wc1p);
        k_conv3<<<512, 512, 0, stream>>>(cur32, curg, wc1p, r3_bc1 + i * EF,
                                         wc2p + (size_t)i * 4 * 4096, r3_bc2 + i * EF,
                                         nxt32, nxtg);
        float* t32 = cur32; cur32 = nxt32; nxt32 = t32;
        short* t16 = curg; curg = nxtg; nxtg = t16;
    }

    // ---- head ----
    k_head<<<MVOX / 64, 512, 0, stream>>>(curg, vox_int, vmin,
                                          lin1p, lin1_b, lin2p, lin2_b, linb_W, linb_b,
                                          (float*)d_out);
}